// Round 1
// baseline (3704.338 us; speedup 1.0000x reference)
//
#include <hip/hip_runtime.h>
#include <hip/hip_bf16.h>

// ---------------- constants (problem shapes) ----------------
constexpr int B   = 4;
constexpr int C   = 1024;   // seq len
constexpr int HH  = 768;    // hidden
constexpr int NHD = 12;     // attention heads
constexpr int E   = 22;     // entities
constexpr int MM  = 3;      // mentions per entity
constexpr int LL  = 30;     // links
constexpr int NN  = 118;    // graph nodes
constexpr int PP  = 462;    // pairs
constexpr int EMB = 512;
constexpr int IC  = 256;
constexpr int LS  = 16;
constexpr int ND  = 532;    // emb + 20 (node feature dim)
constexpr int KCAT = 4*ND + ND; // 2660 (RGCN concat K)

// ---------------- kernels ----------------

// attention mean over heads: (B,h,c,c) -> (B,c,c)
__global__ __launch_bounds__(256) void att_mean_kernel(const float* __restrict__ att,
                                                       float* __restrict__ out) {
    int idx = blockIdx.x * 256 + threadIdx.x;
    if (idx >= B * C * C) return;
    int b = idx / (C * C), rc = idx % (C * C);
    const float* p = att + (size_t)b * NHD * C * C + rc;
    float s = 0.f;
#pragma unroll
    for (int hh = 0; hh < NHD; hh++) s += p[(size_t)hh * C * C];
    out[idx] = s * (1.0f / NHD);
}

// generic fp32 GEMM: C[M,N] = act(A[M,K] @ Bm[K,N] + bias)
// 64x64 tile, BK=16, 256 threads, 4x4 per thread. act: 0 none, 1 relu, 2 tanh
__global__ __launch_bounds__(256) void gemm_kernel(const float* __restrict__ A,
                                                   const float* __restrict__ Bm,
                                                   const float* __restrict__ bias,
                                                   float* __restrict__ Cc,
                                                   int M, int N, int K, int act) {
    __shared__ float As[16][68];
    __shared__ float Bs[16][68];
    int tid = threadIdx.x;
    int tx = tid & 15, ty = tid >> 4;
    int row0 = blockIdx.y * 64, col0 = blockIdx.x * 64;
    float acc[4][4] = {};
    for (int k0 = 0; k0 < K; k0 += 16) {
#pragma unroll
        for (int pass = 0; pass < 4; pass++) {
            int r = pass * 16 + (tid >> 4);
            int gr = row0 + r, gk = k0 + (tid & 15);
            As[tid & 15][r] = (gr < M && gk < K) ? A[(size_t)gr * K + gk] : 0.f;
        }
#pragma unroll
        for (int pass = 0; pass < 4; pass++) {
            int kk = pass * 4 + (tid >> 6);
            int cc = tid & 63;
            int gk = k0 + kk, gc = col0 + cc;
            Bs[kk][cc] = (gk < K && gc < N) ? Bm[(size_t)gk * N + gc] : 0.f;
        }
        __syncthreads();
#pragma unroll
        for (int kk = 0; kk < 16; kk++) {
            float4 av = *(const float4*)&As[kk][ty * 4];
            float4 bv = *(const float4*)&Bs[kk][tx * 4];
            float a[4] = {av.x, av.y, av.z, av.w};
            float bb[4] = {bv.x, bv.y, bv.z, bv.w};
#pragma unroll
            for (int i = 0; i < 4; i++)
#pragma unroll
                for (int j = 0; j < 4; j++) acc[i][j] += a[i] * bb[j];
        }
        __syncthreads();
    }
#pragma unroll
    for (int i = 0; i < 4; i++) {
        int gr = row0 + ty * 4 + i;
        if (gr >= M) continue;
#pragma unroll
        for (int j = 0; j < 4; j++) {
            int gc = col0 + tx * 4 + j;
            if (gc >= N) continue;
            float v = acc[i][j] + (bias ? bias[gc] : 0.f);
            if (act == 1) v = fmaxf(v, 0.f);
            else if (act == 2) v = tanhf(v);
            Cc[(size_t)gr * N + gc] = v;
        }
    }
}

// fill nodes rows 0..87 (entity logsumexp + mention copies) and type-embed cols for ALL rows
__global__ __launch_bounds__(256) void nodes_fill_kernel(const float* __restrict__ seq,
                                                         const int* __restrict__ mention_idx,
                                                         const int* __restrict__ node_types,
                                                         const float* __restrict__ type_embed,
                                                         float* __restrict__ nodes) {
    int n = blockIdx.x, b = blockIdx.y, t = threadIdx.x;
    float* dst = nodes + ((size_t)b * NN + n) * ND;
    if (n < E) {
        const int* mi = mention_idx + (b * E + n) * MM;
        int i0 = mi[0], i1 = mi[1], i2 = mi[2];
        const float* s0 = seq + ((size_t)b * C + i0) * EMB;
        const float* s1 = seq + ((size_t)b * C + i1) * EMB;
        const float* s2 = seq + ((size_t)b * C + i2) * EMB;
        for (int d = t; d < EMB; d += 256) {
            float v0 = s0[d], v1 = s1[d], v2 = s2[d];
            float mx = fmaxf(v0, fmaxf(v1, v2));
            dst[d] = mx + logf(expf(v0 - mx) + expf(v1 - mx) + expf(v2 - mx));
        }
    } else if (n < E + E * MM) {
        int m = n - E;
        int src = mention_idx[b * E * MM + m];
        const float* sp = seq + ((size_t)b * C + src) * EMB;
        for (int d = t; d < EMB; d += 256) dst[d] = sp[d];
    }
    if (t < 20) {
        int ty_ = node_types[b * NN + n];
        dst[EMB + t] = type_embed[ty_ * 20 + t];
    }
}

// link nodes -> nodes rows 88..117, cols 0..511
__global__ __launch_bounds__(256) void link_nodes_kernel(const float* __restrict__ seq,
                                                         const float* __restrict__ am,
                                                         const int* __restrict__ link_start,
                                                         float* __restrict__ nodes) {
    int l = blockIdx.x, b = blockIdx.y, t = threadIdx.x;
    __shared__ float Ash[LS][LS];
    __shared__ float w[LS];
    int start = link_start[b * LL + l];
    {
        int i = t >> 4, j = t & 15;
        Ash[i][j] = am[((size_t)b * C + start + i) * C + (start + j)];
    }
    __syncthreads();
    if (t < LS) {
        float s = 0.f;
#pragma unroll
        for (int i = 0; i < LS; i++) s += Ash[i][t];
        w[t] = s * (1.0f / LS);
    }
    __syncthreads();
    float* dst = nodes + ((size_t)b * NN + (E + E * MM) + l) * ND;
    for (int d = t; d < EMB; d += 256) {
        float acc = 0.f;
#pragma unroll
        for (int j = 0; j < LS; j++) acc += w[j] * seq[((size_t)b * C + start + j) * EMB + d];
        dst[d] = acc;
    }
}

// ea[b,e,:] = normalize( mean_m att_mean[b, mf[b,e,m], :] )
__global__ __launch_bounds__(256) void ea_kernel(const float* __restrict__ am,
                                                 const int* __restrict__ mention_idx,
                                                 float* __restrict__ ea) {
    int e = blockIdx.x, b = blockIdx.y, t = threadIdx.x;
    const int* mi = mention_idx + (b * E + e) * MM;
    int i0 = mi[0], i1 = mi[1], i2 = mi[2];
    const float* r0 = am + ((size_t)b * C + i0) * C;
    const float* r1 = am + ((size_t)b * C + i1) * C;
    const float* r2 = am + ((size_t)b * C + i2) * C;
    float* dst = ea + ((size_t)b * E + e) * C;
    __shared__ float red[256];
    float psum = 0.f;
    for (int ct = t; ct < C; ct += 256) {
        float v = (r0[ct] + r1[ct] + r2[ct]) * (1.0f / 3.0f);
        dst[ct] = v;
        psum += v;
    }
    red[t] = psum;
    __syncthreads();
    for (int s = 128; s > 0; s >>= 1) {
        if (t < s) red[t] += red[t + s];
        __syncthreads();
    }
    float inv = 1.0f / (red[0] + 1e-5f);
    for (int ct = t; ct < C; ct += 256) dst[ct] *= inv;
}

// e_ctx[b,e,d] = sum_ct ea[b,e,ct] * seq[b,ct,d]
__global__ __launch_bounds__(256) void ectx_kernel(const float* __restrict__ ea,
                                                   const float* __restrict__ seq,
                                                   float* __restrict__ ectx) {
    int b = blockIdx.y, t = threadIdx.x;
    int d = blockIdx.x * 256 + t;
    float acc[E];
#pragma unroll
    for (int e = 0; e < E; e++) acc[e] = 0.f;
    for (int ct = 0; ct < C; ct++) {
        float s = seq[((size_t)b * C + ct) * EMB + d];
#pragma unroll
        for (int e = 0; e < E; e++) acc[e] += ea[((size_t)b * E + e) * C + ct] * s;
    }
#pragma unroll
    for (int e = 0; e < E; e++) ectx[((size_t)b * E + e) * EMB + d] = acc[e];
}

// adjacency row-normalize
__global__ __launch_bounds__(128) void adjn_kernel(const float* __restrict__ adj,
                                                   float* __restrict__ adjn) {
    int row = blockIdx.x;  // b*4*NN rows
    int t = threadIdx.x;
    const float* src = adj + (size_t)row * NN;
    __shared__ float red[128];
    float s = (t < NN) ? src[t] : 0.f;
    red[t] = s;
    __syncthreads();
    for (int st = 64; st > 0; st >>= 1) {
        if (t < st) red[t] += red[t + st];
        __syncthreads();
    }
    float inv = 1.0f / (red[0] + 1e-5f);
    if (t < NN) adjn[(size_t)row * NN + t] = src[t] * inv;
}

// msg[b,r,i,:] = sum_j adjn[b,r,i,j]*nodes[b,j,:]  -> Arow[b*NN+i][r*ND + d]
// also (r==0) copies nodes row into Arow cols 4*ND..
__global__ __launch_bounds__(256) void msg_kernel(const float* __restrict__ adjn,
                                                  const float* __restrict__ nodes,
                                                  float* __restrict__ Arow) {
    int i = blockIdx.x, r = blockIdx.y, b = blockIdx.z;
    int t = threadIdx.x;
    __shared__ float a_sh[NN];
    if (t < NN) a_sh[t] = adjn[(((size_t)b * 4 + r) * NN + i) * NN + t];
    __syncthreads();
    float* dst = Arow + ((size_t)b * NN + i) * KCAT;
    const float* nb = nodes + (size_t)b * NN * ND;
    for (int d = t; d < ND; d += 256) {
        float acc = 0.f;
        for (int j = 0; j < NN; j++) acc += a_sh[j] * nb[(size_t)j * ND + d];
        dst[r * ND + d] = acc;
        if (r == 0) dst[4 * ND + d] = nb[(size_t)i * ND + d];
    }
}

// x[b,d,i,k] = ent[i,d]*ent[k,d] + ectx[i,d]*ectx[k,d]
__global__ __launch_bounds__(512) void pairwise_kernel(const float* __restrict__ gcn,
                                                       const float* __restrict__ ectx,
                                                       float* __restrict__ x) {
    int d = blockIdx.x, b = blockIdx.y, t = threadIdx.x;
    __shared__ float ev[E], cv[E];
    if (t < E) ev[t] = gcn[((size_t)b * NN + t) * EMB + d];
    else if (t < 2 * E) cv[t - E] = ectx[((size_t)b * E + (t - E)) * EMB + d];
    __syncthreads();
    if (t < E * E) {
        int i = t / E, k = t % E;
        x[((size_t)b * EMB + d) * (E * E) + t] = ev[i] * ev[k] + cv[i] * cv[k];
    }
}

// direct 5x5 SAME conv on 22x22, NCHW, relu. COUT_TILE=2, CIN_TILE=4.
__global__ __launch_bounds__(256) void conv5_kernel(const float* __restrict__ in,
                                                    const float* __restrict__ w,
                                                    const float* __restrict__ bias,
                                                    float* __restrict__ out,
                                                    int Cin, int Cout) {
    int co0 = blockIdx.x * 2, b = blockIdx.y;
    int t = threadIdx.x;
    __shared__ float tile[4][676];  // 4 padded planes of 26x26
    int oh = t / 11, ow0 = (t % 11) * 2;
    bool active = (t < 242);
    float acc00 = 0.f, acc01 = 0.f, acc10 = 0.f, acc11 = 0.f;
    const float* inb = in + (size_t)b * Cin * 484;
    for (int c0 = 0; c0 < Cin; c0 += 4) {
        __syncthreads();
        for (int idx = t; idx < 4 * 676; idx += 256) {
            int p = idx / 676, off = idx % 676;
            int r = off / 26, cc = off % 26;
            int ih = r - 2, iw = cc - 2;
            float v = 0.f;
            if (ih >= 0 && ih < 22 && iw >= 0 && iw < 22)
                v = inb[((size_t)(c0 + p) * 22 + ih) * 22 + iw];
            tile[p][off] = v;
        }
        __syncthreads();
        if (active) {
#pragma unroll
            for (int p = 0; p < 4; p++) {
                const float* w0 = w + ((size_t)co0 * Cin + (c0 + p)) * 25;
                const float* w1 = w0 + (size_t)Cin * 25;
#pragma unroll
                for (int r = 0; r < 5; r++) {
                    const float* trow = &tile[p][(oh + r) * 26 + ow0];
                    float iv[6];
#pragma unroll
                    for (int s = 0; s < 6; s++) iv[s] = trow[s];
#pragma unroll
                    for (int s = 0; s < 5; s++) {
                        float wa = w0[r * 5 + s], wb = w1[r * 5 + s];
                        acc00 += wa * iv[s];
                        acc01 += wa * iv[s + 1];
                        acc10 += wb * iv[s];
                        acc11 += wb * iv[s + 1];
                    }
                }
            }
        }
    }
    if (active) {
        float b0 = bias[co0], b1 = bias[co0 + 1];
        float* o0 = out + (((size_t)b * Cout + co0) * 22 + oh) * 22 + ow0;
        float* o1 = o0 + 484;
        o0[0] = fmaxf(acc00 + b0, 0.f);
        o0[1] = fmaxf(acc01 + b0, 0.f);
        o1[0] = fmaxf(acc10 + b1, 0.f);
        o1[1] = fmaxf(acc11 + b1, 0.f);
    }
}

// transpose per-b: [512][484] -> [484][512]
__global__ __launch_bounds__(256) void transpose_kernel(const float* __restrict__ x3,
                                                        float* __restrict__ mflat) {
    __shared__ float tl[32][33];
    int b = blockIdx.z;
    int d0 = blockIdx.x * 32, s0 = blockIdx.y * 32;
    int tx = threadIdx.x % 32, ty = threadIdx.x / 32;
    for (int i = ty; i < 32; i += 8) {
        int d = d0 + i, s = s0 + tx;
        tl[i][tx] = (d < EMB && s < 484) ? x3[((size_t)b * EMB + d) * 484 + s] : 0.f;
    }
    __syncthreads();
    for (int i = ty; i < 32; i += 8) {
        int s = s0 + i, d = d0 + tx;
        if (s < 484 && d < EMB) mflat[((size_t)b * 484 + s) * EMB + d] = tl[tx][i];
    }
}

// feat[b,p,:] = [hs, ts, mfe, hs*ts]
__global__ __launch_bounds__(256) void feat_kernel(const float* __restrict__ gcn,
                                                   const float* __restrict__ mflat,
                                                   const int* __restrict__ hts,
                                                   float* __restrict__ feat) {
    int p = blockIdx.x, b = blockIdx.y, t = threadIdx.x;
    int hi = hts[((size_t)b * PP + p) * 2];
    int ti = hts[((size_t)b * PP + p) * 2 + 1];
    const float* hsrc = gcn + ((size_t)b * NN + hi) * EMB;
    const float* tsrc = gcn + ((size_t)b * NN + ti) * EMB;
    const float* msrc = mflat + ((size_t)b * 484 + hi * E + ti) * EMB;
    float* dst = feat + ((size_t)b * PP + p) * (4 * EMB);
    for (int d = t; d < EMB; d += 256) {
        float hv = hsrc[d], tv = tsrc[d];
        dst[d] = hv;
        dst[EMB + d] = tv;
        dst[2 * EMB + d] = msrc[d];
        dst[3 * EMB + d] = hv * tv;
    }
}

// ---------------- launcher ----------------
extern "C" void kernel_launch(void* const* d_in, const int* in_sizes, int n_in,
                              void* d_out, int out_size, void* d_ws, size_t ws_size,
                              hipStream_t stream) {
    const float* sequence_output = (const float*)d_in[0];
    const float* attention      = (const float*)d_in[1];
    const float* adjacency      = (const float*)d_in[2];
    const int*   mention_idx    = (const int*)d_in[3];
    const int*   link_start     = (const int*)d_in[4];
    const int*   node_types     = (const int*)d_in[5];
    const int*   hts            = (const int*)d_in[6];
    const float* W_trans        = (const float*)d_in[7];
    const float* b_trans        = (const float*)d_in[8];
    const float* type_embed     = (const float*)d_in[9];
    const float* W_rel          = (const float*)d_in[10];
    const float* W_self         = (const float*)d_in[11];
    const float* b_rgcn         = (const float*)d_in[12];
    const float* conv1_w        = (const float*)d_in[13];
    const float* conv1_b        = (const float*)d_in[14];
    const float* conv2_w        = (const float*)d_in[15];
    const float* conv2_b        = (const float*)d_in[16];
    const float* conv3_w        = (const float*)d_in[17];
    const float* conv3_b        = (const float*)d_in[18];
    const float* ht_W           = (const float*)d_in[19];
    const float* ht_b           = (const float*)d_in[20];
    const float* bil_W          = (const float*)d_in[21];
    const float* bil_b          = (const float*)d_in[22];
    float* out = (float*)d_out;
    float* ws = (float*)d_ws;

    // ---- workspace layout (floats), with lifetime-based aliasing ----
    // region1 [0 .. 4,194,304): att_mean; later conv buffers + mflat
    float* att_mean = ws;                          // 4,194,304 (B*C*C)
    float* xbuf  = ws;                             // B*512*484 = 991,232
    float* y1    = ws + 991232;                    // 495,616
    float* y2    = ws + 1486848;                   // 495,616
    float* y3    = ws + 1982464;                   // 991,232
    float* mflat = ws + 2973696;                   // 991,232 (ends 3,964,928)
    float* seqb  = ws + 4194304;                   // 2,097,152 (B*C*EMB); later ht
    float* htbuf = seqb;                           // 1,892,352 (B*P*1024)
    float* nodes = ws + 6291456;                   // 251,104
    float* adjn  = ws + 6542560;                   // 222,784 (dead after msg)
    float* gcnb  = ws + 6542560;                   // 241,664 (written after adjn/ea dead)
    float* ea    = ws + 6765344;                   // 90,112 (dead after ectx)
    float* ectx  = ws + 6855456;                   // 45,056
    float* Arow  = ws + 6900512;                   // 1,255,520
    float* Bcat  = ws + 8156032;                   // 1,361,920 (ends 9,517,952)
    float* feat  = ws + 6900512;                   // 3,784,704 (over Arow+Bcat, after gcn gemm)

    // 1. att_mean
    att_mean_kernel<<<(B * C * C + 255) / 256, 256, 0, stream>>>(attention, att_mean);
    // 2. seq = sequence_output @ W_trans + b_trans   (M=4096, N=512, K=768)
    gemm_kernel<<<dim3(EMB / 64, (B * C) / 64), 256, 0, stream>>>(
        sequence_output, W_trans, b_trans, seqb, B * C, EMB, HH, 0);
    // 3. nodes: entity lse + mention rows + type cols
    nodes_fill_kernel<<<dim3(NN, B), 256, 0, stream>>>(seqb, mention_idx, node_types,
                                                       type_embed, nodes);
    // 4. link node rows
    link_nodes_kernel<<<dim3(LL, B), 256, 0, stream>>>(seqb, att_mean, link_start, nodes);
    // 5. ea (normalized entity attention over context)
    ea_kernel<<<dim3(E, B), 256, 0, stream>>>(att_mean, mention_idx, ea);
    // 6. e_ctx = ea @ seq
    ectx_kernel<<<dim3(EMB / 256, B), 256, 0, stream>>>(ea, seqb, ectx);
    // 7. adjacency normalize
    adjn_kernel<<<B * 4 * NN, 128, 0, stream>>>(adjacency, adjn);
    // 8. msg -> Arow (concat layout, incl. nodes copy)
    msg_kernel<<<dim3(NN, 4, B), 256, 0, stream>>>(adjn, nodes, Arow);
    // 9. Bcat = [W_rel (2128x512); W_self (532x512)]
    hipMemcpyAsync(Bcat, W_rel, (size_t)4 * ND * EMB * sizeof(float),
                   hipMemcpyDeviceToDevice, stream);
    hipMemcpyAsync(Bcat + (size_t)4 * ND * EMB, W_self, (size_t)ND * EMB * sizeof(float),
                   hipMemcpyDeviceToDevice, stream);
    // 10. gcn = relu(Arow @ Bcat + b_rgcn)   (M=472, N=512, K=2660)
    gemm_kernel<<<dim3(8, 8), 256, 0, stream>>>(Arow, Bcat, b_rgcn, gcnb, B * NN, EMB,
                                                KCAT, 1);
    // 11. x[b,d,i,k]
    pairwise_kernel<<<dim3(EMB, B), 512, 0, stream>>>(gcnb, ectx, xbuf);
    // 12-14. convs (relu)
    conv5_kernel<<<dim3(IC / 2, B), 256, 0, stream>>>(xbuf, conv1_w, conv1_b, y1, 512, 256);
    conv5_kernel<<<dim3(IC / 2, B), 256, 0, stream>>>(y1, conv2_w, conv2_b, y2, 256, 256);
    conv5_kernel<<<dim3(EMB / 2, B), 256, 0, stream>>>(y2, conv3_w, conv3_b, y3, 256, 512);
    // 15. mflat = transpose(y3)
    transpose_kernel<<<dim3(16, 16, B), 256, 0, stream>>>(y3, mflat);
    // 16. feat gather
    feat_kernel<<<dim3(PP, B), 256, 0, stream>>>(gcnb, mflat, hts, feat);
    // 17. ht = tanh(feat @ ht_W + ht_b)   (M=1848, N=1024, K=2048)
    gemm_kernel<<<dim3(16, 29), 256, 0, stream>>>(feat, ht_W, ht_b, htbuf, B * PP, 1024,
                                                  2048, 2);
    // 18. out = ht @ bil_W + bil_b   (M=1848, N=97, K=1024)
    gemm_kernel<<<dim3(2, 29), 256, 0, stream>>>(htbuf, bil_W, bil_b, out, B * PP, 97,
                                                 1024, 0);
}

// Round 3
// 2958.292 us; speedup vs baseline: 1.2522x; 1.2522x over previous
//
#include <hip/hip_runtime.h>
#include <hip/hip_bf16.h>

// ---------------- constants (problem shapes) ----------------
constexpr int B   = 4;
constexpr int C   = 1024;   // seq len
constexpr int HH  = 768;    // hidden
constexpr int NHD = 12;     // attention heads
constexpr int E   = 22;     // entities
constexpr int MM  = 3;      // mentions per entity
constexpr int LL  = 30;     // links
constexpr int NN  = 118;    // graph nodes
constexpr int PP  = 462;    // pairs
constexpr int EMB = 512;
constexpr int IC  = 256;
constexpr int LS  = 16;
constexpr int ND  = 532;    // emb + 20 (node feature dim)
constexpr int KCAT = 4*ND + ND; // 2660 (RGCN concat K)

// ---------------- kernels ----------------

// attention mean over heads, vectorized: (B,h,c,c) -> (B,c,c)
__global__ __launch_bounds__(256) void att_mean4_kernel(const float4* __restrict__ att,
                                                        float4* __restrict__ out) {
    int idx = blockIdx.x * 256 + threadIdx.x;
    int tot = B * C * C / 4;
    if (idx >= tot) return;
    int b = idx / (C * C / 4), rc = idx % (C * C / 4);
    const float4* p = att + (size_t)b * NHD * (C * C / 4) + rc;
    float sx = 0.f, sy = 0.f, sz = 0.f, sw = 0.f;
#pragma unroll
    for (int hh = 0; hh < NHD; hh++) {
        float4 v = p[(size_t)hh * (C * C / 4)];
        sx += v.x; sy += v.y; sz += v.z; sw += v.w;
    }
    const float inv = 1.0f / NHD;
    float4 r; r.x = sx * inv; r.y = sy * inv; r.z = sz * inv; r.w = sw * inv;
    out[idx] = r;
}

// generic fp32 GEMM: C[M,N] = act(A[M,K] @ Bm[K,N] + bias)
// 64x64 tile, BK=16, 256 threads, 4x4 per thread. act: 0 none, 1 relu, 2 tanh
__global__ __launch_bounds__(256) void gemm_kernel(const float* __restrict__ A,
                                                   const float* __restrict__ Bm,
                                                   const float* __restrict__ bias,
                                                   float* __restrict__ Cc,
                                                   int M, int N, int K, int act) {
    __shared__ __align__(16) float As[16][68];
    __shared__ __align__(16) float Bs[16][68];
    int tid = threadIdx.x;
    int tx = tid & 15, ty = tid >> 4;
    int row0 = blockIdx.y * 64, col0 = blockIdx.x * 64;
    float acc[4][4] = {};
    for (int k0 = 0; k0 < K; k0 += 16) {
#pragma unroll
        for (int pass = 0; pass < 4; pass++) {
            int r = pass * 16 + (tid >> 4);
            int gr = row0 + r, gk = k0 + (tid & 15);
            As[tid & 15][r] = (gr < M && gk < K) ? A[(size_t)gr * K + gk] : 0.f;
        }
#pragma unroll
        for (int pass = 0; pass < 4; pass++) {
            int kk = pass * 4 + (tid >> 6);
            int cc = tid & 63;
            int gk = k0 + kk, gc = col0 + cc;
            Bs[kk][cc] = (gk < K && gc < N) ? Bm[(size_t)gk * N + gc] : 0.f;
        }
        __syncthreads();
#pragma unroll
        for (int kk = 0; kk < 16; kk++) {
            float4 av = *(const float4*)&As[kk][ty * 4];
            float4 bv = *(const float4*)&Bs[kk][tx * 4];
            float a[4] = {av.x, av.y, av.z, av.w};
            float bb[4] = {bv.x, bv.y, bv.z, bv.w};
#pragma unroll
            for (int i = 0; i < 4; i++)
#pragma unroll
                for (int j = 0; j < 4; j++) acc[i][j] += a[i] * bb[j];
        }
        __syncthreads();
    }
#pragma unroll
    for (int i = 0; i < 4; i++) {
        int gr = row0 + ty * 4 + i;
        if (gr >= M) continue;
#pragma unroll
        for (int j = 0; j < 4; j++) {
            int gc = col0 + tx * 4 + j;
            if (gc >= N) continue;
            float v = acc[i][j] + (bias ? bias[gc] : 0.f);
            if (act == 1) v = fmaxf(v, 0.f);
            else if (act == 2) v = tanhf(v);
            Cc[(size_t)gr * N + gc] = v;
        }
    }
}

// batched variant (blockIdx.z = batch) for small per-batch GEMMs (e_ctx)
__global__ __launch_bounds__(256) void gemmb_kernel(const float* __restrict__ A0,
                                                    const float* __restrict__ B0,
                                                    float* __restrict__ C0,
                                                    int M, int N, int K,
                                                    long sA, long sB, long sC) {
    const float* A = A0 + (size_t)blockIdx.z * sA;
    const float* Bm = B0 + (size_t)blockIdx.z * sB;
    float* Cc = C0 + (size_t)blockIdx.z * sC;
    __shared__ __align__(16) float As[16][68];
    __shared__ __align__(16) float Bs[16][68];
    int tid = threadIdx.x;
    int tx = tid & 15, ty = tid >> 4;
    int row0 = blockIdx.y * 64, col0 = blockIdx.x * 64;
    float acc[4][4] = {};
    for (int k0 = 0; k0 < K; k0 += 16) {
#pragma unroll
        for (int pass = 0; pass < 4; pass++) {
            int r = pass * 16 + (tid >> 4);
            int gr = row0 + r, gk = k0 + (tid & 15);
            As[tid & 15][r] = (gr < M && gk < K) ? A[(size_t)gr * K + gk] : 0.f;
        }
#pragma unroll
        for (int pass = 0; pass < 4; pass++) {
            int kk = pass * 4 + (tid >> 6);
            int cc = tid & 63;
            int gk = k0 + kk, gc = col0 + cc;
            Bs[kk][cc] = (gk < K && gc < N) ? Bm[(size_t)gk * N + gc] : 0.f;
        }
        __syncthreads();
#pragma unroll
        for (int kk = 0; kk < 16; kk++) {
            float4 av = *(const float4*)&As[kk][ty * 4];
            float4 bv = *(const float4*)&Bs[kk][tx * 4];
            float a[4] = {av.x, av.y, av.z, av.w};
            float bb[4] = {bv.x, bv.y, bv.z, bv.w};
#pragma unroll
            for (int i = 0; i < 4; i++)
#pragma unroll
                for (int j = 0; j < 4; j++) acc[i][j] += a[i] * bb[j];
        }
        __syncthreads();
    }
#pragma unroll
    for (int i = 0; i < 4; i++) {
        int gr = row0 + ty * 4 + i;
        if (gr >= M) continue;
#pragma unroll
        for (int j = 0; j < 4; j++) {
            int gc = col0 + tx * 4 + j;
            if (gc >= N) continue;
            Cc[(size_t)gr * N + gc] = acc[i][j];
        }
    }
}

// fill nodes rows 0..87 (entity logsumexp + mention copies) and type-embed cols for ALL rows
__global__ __launch_bounds__(256) void nodes_fill_kernel(const float* __restrict__ seq,
                                                         const int* __restrict__ mention_idx,
                                                         const int* __restrict__ node_types,
                                                         const float* __restrict__ type_embed,
                                                         float* __restrict__ nodes) {
    int n = blockIdx.x, b = blockIdx.y, t = threadIdx.x;
    float* dst = nodes + ((size_t)b * NN + n) * ND;
    if (n < E) {
        const int* mi = mention_idx + (b * E + n) * MM;
        int i0 = mi[0], i1 = mi[1], i2 = mi[2];
        const float* s0 = seq + ((size_t)b * C + i0) * EMB;
        const float* s1 = seq + ((size_t)b * C + i1) * EMB;
        const float* s2 = seq + ((size_t)b * C + i2) * EMB;
        for (int d = t; d < EMB; d += 256) {
            float v0 = s0[d], v1 = s1[d], v2 = s2[d];
            float mx = fmaxf(v0, fmaxf(v1, v2));
            dst[d] = mx + logf(expf(v0 - mx) + expf(v1 - mx) + expf(v2 - mx));
        }
    } else if (n < E + E * MM) {
        int m = n - E;
        int src = mention_idx[b * E * MM + m];
        const float* sp = seq + ((size_t)b * C + src) * EMB;
        for (int d = t; d < EMB; d += 256) dst[d] = sp[d];
    }
    if (t < 20) {
        int ty_ = node_types[b * NN + n];
        dst[EMB + t] = type_embed[ty_ * 20 + t];
    }
}

// link nodes -> nodes rows 88..117, cols 0..511
__global__ __launch_bounds__(256) void link_nodes_kernel(const float* __restrict__ seq,
                                                         const float* __restrict__ am,
                                                         const int* __restrict__ link_start,
                                                         float* __restrict__ nodes) {
    int l = blockIdx.x, b = blockIdx.y, t = threadIdx.x;
    __shared__ float Ash[LS][LS];
    __shared__ float w[LS];
    int start = link_start[b * LL + l];
    {
        int i = t >> 4, j = t & 15;
        Ash[i][j] = am[((size_t)b * C + start + i) * C + (start + j)];
    }
    __syncthreads();
    if (t < LS) {
        float s = 0.f;
#pragma unroll
        for (int i = 0; i < LS; i++) s += Ash[i][t];
        w[t] = s * (1.0f / LS);
    }
    __syncthreads();
    float* dst = nodes + ((size_t)b * NN + (E + E * MM) + l) * ND;
    for (int d = t; d < EMB; d += 256) {
        float acc = 0.f;
#pragma unroll
        for (int j = 0; j < LS; j++) acc += w[j] * seq[((size_t)b * C + start + j) * EMB + d];
        dst[d] = acc;
    }
}

// ea[b,e,:] = normalize( mean_m att_mean[b, mf[b,e,m], :] )
__global__ __launch_bounds__(256) void ea_kernel(const float* __restrict__ am,
                                                 const int* __restrict__ mention_idx,
                                                 float* __restrict__ ea) {
    int e = blockIdx.x, b = blockIdx.y, t = threadIdx.x;
    const int* mi = mention_idx + (b * E + e) * MM;
    int i0 = mi[0], i1 = mi[1], i2 = mi[2];
    const float* r0 = am + ((size_t)b * C + i0) * C;
    const float* r1 = am + ((size_t)b * C + i1) * C;
    const float* r2 = am + ((size_t)b * C + i2) * C;
    float* dst = ea + ((size_t)b * E + e) * C;
    __shared__ float red[256];
    float psum = 0.f;
    for (int ct = t; ct < C; ct += 256) {
        float v = (r0[ct] + r1[ct] + r2[ct]) * (1.0f / 3.0f);
        dst[ct] = v;
        psum += v;
    }
    red[t] = psum;
    __syncthreads();
    for (int s = 128; s > 0; s >>= 1) {
        if (t < s) red[t] += red[t + s];
        __syncthreads();
    }
    float inv = 1.0f / (red[0] + 1e-5f);
    for (int ct = t; ct < C; ct += 256) dst[ct] *= inv;
}

// adjacency row-normalize
__global__ __launch_bounds__(128) void adjn_kernel(const float* __restrict__ adj,
                                                   float* __restrict__ adjn) {
    int row = blockIdx.x;  // b*4*NN rows
    int t = threadIdx.x;
    const float* src = adj + (size_t)row * NN;
    __shared__ float red[128];
    float s = (t < NN) ? src[t] : 0.f;
    red[t] = s;
    __syncthreads();
    for (int st = 64; st > 0; st >>= 1) {
        if (t < st) red[t] += red[t + st];
        __syncthreads();
    }
    float inv = 1.0f / (red[0] + 1e-5f);
    if (t < NN) adjn[(size_t)row * NN + t] = src[t] * inv;
}

// msg[b,r,i,:] = sum_j adjn[b,r,i,j]*nodes[b,j,:]  -> Arow[b*NN+i][r*ND + d]
__global__ __launch_bounds__(256) void msg_kernel(const float* __restrict__ adjn,
                                                  const float* __restrict__ nodes,
                                                  float* __restrict__ Arow) {
    int i = blockIdx.x, r = blockIdx.y, b = blockIdx.z;
    int t = threadIdx.x;
    __shared__ float a_sh[NN];
    if (t < NN) a_sh[t] = adjn[(((size_t)b * 4 + r) * NN + i) * NN + t];
    __syncthreads();
    float* dst = Arow + ((size_t)b * NN + i) * KCAT;
    const float* nb = nodes + (size_t)b * NN * ND;
    for (int d = t; d < ND; d += 256) {
        float acc = 0.f;
        for (int j = 0; j < NN; j++) acc += a_sh[j] * nb[(size_t)j * ND + d];
        dst[r * ND + d] = acc;
        if (r == 0) dst[4 * ND + d] = nb[(size_t)i * ND + d];
    }
}

// x[b,d,i,k] = ent[i,d]*ent[k,d] + ectx[i,d]*ectx[k,d]
__global__ __launch_bounds__(512) void pairwise_kernel(const float* __restrict__ gcn,
                                                       const float* __restrict__ ectx,
                                                       float* __restrict__ x) {
    int d = blockIdx.x, b = blockIdx.y, t = threadIdx.x;
    __shared__ float ev[E], cv[E];
    if (t < E) ev[t] = gcn[((size_t)b * NN + t) * EMB + d];
    else if (t < 2 * E) cv[t - E] = ectx[((size_t)b * E + (t - E)) * EMB + d];
    __syncthreads();
    if (t < E * E) {
        int i = t / E, k = t % E;
        x[((size_t)b * EMB + d) * (E * E) + t] = ev[i] * ev[k] + cv[i] * cv[k];
    }
}

// implicit-GEMM 5x5 SAME conv on 22x22, chunked over cin.
// block: 64 couts x 64 positions, 16x16 threads, 4x4 micro-tile.
// grid: (Cout/64, 8 pos-tiles, B*nchunk). Partials to part[z][Cout][484].
__global__ __launch_bounds__(256) void conv5g_kernel(const float* __restrict__ in,
                                                     const float* __restrict__ w,
                                                     float* __restrict__ part,
                                                     int Cin, int Cout, int CH) {
    int nch = Cin / CH;
    int z = blockIdx.z;
    int b = z / nch, ch = z % nch;
    int co0 = blockIdx.x * 64;
    int p0 = blockIdx.y * 64;
    int t = threadIdx.x;
    int tx = t & 15, ty = t >> 4;
    int r0 = p0 / 22;
    __shared__ __align__(16) float As[25 * 68];   // [tap][co], stride 68
    __shared__ __align__(16) float Pl[8 * 28];    // 8 padded input rows x 26 cols
    int ohj[4], owj[4];
    bool vj[4];
#pragma unroll
    for (int j = 0; j < 4; j++) {
        int p = p0 + tx * 4 + j;
        vj[j] = p < 484;
        int pc = vj[j] ? p : 483;
        ohj[j] = pc / 22 - r0;   // 0..3
        owj[j] = pc % 22;
    }
    float acc[4][4] = {};
    const float* inb = in + ((size_t)b * Cin + ch * CH) * 484;
    const float* wb = w + ((size_t)co0 * Cin + ch * CH) * 25;
    for (int ci = 0; ci < CH; ci++) {
        __syncthreads();
        if (t < 208) {
            int rr = t / 26, cc = t % 26;
            int ih = r0 - 2 + rr, iw = cc - 2;
            float v = 0.f;
            if (ih >= 0 && ih < 22 && iw >= 0 && iw < 22)
                v = inb[(size_t)ci * 484 + ih * 22 + iw];
            Pl[rr * 28 + cc] = v;
        }
        for (int idx = t; idx < 1600; idx += 256) {
            int co = idx / 25, tap = idx % 25;
            As[tap * 68 + co] = wb[(size_t)co * Cin * 25 + (size_t)ci * 25 + tap];
        }
        __syncthreads();
#pragma unroll
        for (int tap = 0; tap < 25; tap++) {
            int dy = tap / 5, dx = tap % 5;
            float4 av = *(const float4*)&As[tap * 68 + ty * 4];
            float a[4] = {av.x, av.y, av.z, av.w};
            float bv[4];
#pragma unroll
            for (int j = 0; j < 4; j++)
                bv[j] = Pl[(ohj[j] + dy) * 28 + owj[j] + dx];
#pragma unroll
            for (int i = 0; i < 4; i++)
#pragma unroll
                for (int j = 0; j < 4; j++) acc[i][j] += a[i] * bv[j];
        }
    }
    float* dst = part + ((size_t)z * Cout + co0) * 484;
#pragma unroll
    for (int i = 0; i < 4; i++) {
#pragma unroll
        for (int j = 0; j < 4; j++) {
            if (vj[j])
                dst[(size_t)(ty * 4 + i) * 484 + p0 + tx * 4 + j] = acc[i][j];
        }
    }
}

// out[b,co,p] = relu(bias[co] + sum_ch part[(b*nch+ch),co,p])
__global__ __launch_bounds__(256) void reduce_bias_relu_kernel(const float* __restrict__ part,
                                                               const float* __restrict__ bias,
                                                               float* __restrict__ out,
                                                               int Cout, int nch) {
    int idx = blockIdx.x * 256 + threadIdx.x;
    int total = B * Cout * 484;
    if (idx >= total) return;
    int b = idx / (Cout * 484);
    int rem = idx % (Cout * 484);
    int co = rem / 484;
    float s = bias[co];
    const float* p = part + ((size_t)b * nch) * Cout * 484 + rem;
    for (int ch = 0; ch < nch; ch++) s += p[(size_t)ch * Cout * 484];
    out[idx] = fmaxf(s, 0.f);
}

// conv3 reduce + bias + relu + transpose to mflat[(b*484+p)*512+co]  (Cout=512)
__global__ __launch_bounds__(256) void reduce3_transpose_kernel(const float* __restrict__ part,
                                                                const float* __restrict__ bias,
                                                                float* __restrict__ mflat,
                                                                int nch) {
    __shared__ float tl[32][33];
    int b = blockIdx.z;
    int co0 = blockIdx.x * 32, pp0 = blockIdx.y * 32;
    int tx = threadIdx.x % 32, tyy = threadIdx.x / 32;
    for (int i = tyy; i < 32; i += 8) {
        int co = co0 + i, p = pp0 + tx;
        float v = 0.f;
        if (p < 484) {
            v = bias[co];
            const float* src = part + (((size_t)b * nch) * 512 + co) * 484 + p;
            for (int ch = 0; ch < nch; ch++) v += src[(size_t)ch * 512 * 484];
            v = fmaxf(v, 0.f);
        }
        tl[i][tx] = v;
    }
    __syncthreads();
    for (int i = tyy; i < 32; i += 8) {
        int p = pp0 + i, co = co0 + tx;
        if (p < 484) mflat[((size_t)b * 484 + p) * 512 + co] = tl[tx][i];
    }
}

// feat[b,p,:] = [hs, ts, mfe, hs*ts]
__global__ __launch_bounds__(256) void feat_kernel(const float* __restrict__ gcn,
                                                   const float* __restrict__ mflat,
                                                   const int* __restrict__ hts,
                                                   float* __restrict__ feat) {
    int p = blockIdx.x, b = blockIdx.y, t = threadIdx.x;
    int hi = hts[((size_t)b * PP + p) * 2];
    int ti = hts[((size_t)b * PP + p) * 2 + 1];
    const float* hsrc = gcn + ((size_t)b * NN + hi) * EMB;
    const float* tsrc = gcn + ((size_t)b * NN + ti) * EMB;
    const float* msrc = mflat + ((size_t)b * 484 + hi * E + ti) * EMB;
    float* dst = feat + ((size_t)b * PP + p) * (4 * EMB);
    for (int d = t; d < EMB; d += 256) {
        float hv = hsrc[d], tv = tsrc[d];
        dst[d] = hv;
        dst[EMB + d] = tv;
        dst[2 * EMB + d] = msrc[d];
        dst[3 * EMB + d] = hv * tv;
    }
}

// ---------------- launcher ----------------
extern "C" void kernel_launch(void* const* d_in, const int* in_sizes, int n_in,
                              void* d_out, int out_size, void* d_ws, size_t ws_size,
                              hipStream_t stream) {
    const float* sequence_output = (const float*)d_in[0];
    const float* attention      = (const float*)d_in[1];
    const float* adjacency      = (const float*)d_in[2];
    const int*   mention_idx    = (const int*)d_in[3];
    const int*   link_start     = (const int*)d_in[4];
    const int*   node_types    = (const int*)d_in[5];
    const int*   hts            = (const int*)d_in[6];
    const float* W_trans        = (const float*)d_in[7];
    const float* b_trans        = (const float*)d_in[8];
    const float* type_embed     = (const float*)d_in[9];
    const float* W_rel          = (const float*)d_in[10];
    const float* W_self         = (const float*)d_in[11];
    const float* b_rgcn         = (const float*)d_in[12];
    const float* conv1_w        = (const float*)d_in[13];
    const float* conv1_b        = (const float*)d_in[14];
    const float* conv2_w        = (const float*)d_in[15];
    const float* conv2_b        = (const float*)d_in[16];
    const float* conv3_w        = (const float*)d_in[17];
    const float* conv3_b        = (const float*)d_in[18];
    const float* ht_W           = (const float*)d_in[19];
    const float* ht_b           = (const float*)d_in[20];
    const float* bil_W          = (const float*)d_in[21];
    const float* bil_b          = (const float*)d_in[22];
    float* out = (float*)d_out;
    float* ws = (float*)d_ws;

    // ---- workspace layout (float offsets), lifetime-aliased ----
    // Region A [0 .. 4,194,304): att_mean (steps 1-5)
    //   then Arow@0 (1,255,520) + Bcat@1,255,520 (1,361,920) (steps 8-10)
    //   then xbuf@0 (991,232), y1@991,232 (495,616), y2@1,486,848 (495,616) (steps 11-14)
    //   then feat@0 (3,784,704) (steps 16-17)
    float* att_mean = ws;
    float* Arow  = ws;
    float* Bcat  = ws + 1255520;
    float* xbuf  = ws;
    float* y1    = ws + 991232;
    float* y2    = ws + 1486848;
    float* feat  = ws;
    // Region B [4,194,304 .. 6,291,456): seqb (steps 2-6), part (12-15), htbuf (17-18)
    float* seqb  = ws + 4194304;   // 2,097,152
    float* part  = ws + 4194304;   // 1,982,464
    float* htbuf = ws + 4194304;   // 1,892,352
    // Region C: persistent small buffers
    float* mflat = ws + 6291456;   // 991,232  -> ends 7,282,688
    float* nodes = ws + 7282688;   // 251,104  -> ends 7,533,792
    float* adjn  = ws + 7533792;   // 222,784  -> ends 7,756,576
    float* ea    = ws + 7756576;   // 90,112   -> ends 7,846,688
    float* ectx  = ws + 7846688;   // 45,056   -> ends 7,891,744
    float* gcnb  = ws + 7891744;   // 241,664  -> ends 8,133,408 (32.5 MB)

    // 1. att_mean (float4)
    att_mean4_kernel<<<(B * C * C / 4 + 255) / 256, 256, 0, stream>>>(
        (const float4*)attention, (float4*)att_mean);
    // 2. seq = sequence_output @ W_trans + b_trans   (M=4096, N=512, K=768)
    gemm_kernel<<<dim3(EMB / 64, (B * C) / 64), 256, 0, stream>>>(
        sequence_output, W_trans, b_trans, seqb, B * C, EMB, HH, 0);
    // 3. nodes: entity lse + mention rows + type cols
    nodes_fill_kernel<<<dim3(NN, B), 256, 0, stream>>>(seqb, mention_idx, node_types,
                                                       type_embed, nodes);
    // 4. link node rows
    link_nodes_kernel<<<dim3(LL, B), 256, 0, stream>>>(seqb, att_mean, link_start, nodes);
    // 5. ea (normalized entity attention over context)
    ea_kernel<<<dim3(E, B), 256, 0, stream>>>(att_mean, mention_idx, ea);
    // 6. e_ctx = ea @ seq  (batched, M=22, N=512, K=1024)
    gemmb_kernel<<<dim3(EMB / 64, 1, B), 256, 0, stream>>>(
        ea, seqb, ectx, E, EMB, C, (long)E * C, (long)C * EMB, (long)E * EMB);
    // 7. adjacency normalize
    adjn_kernel<<<B * 4 * NN, 128, 0, stream>>>(adjacency, adjn);
    // 8. msg -> Arow (concat layout, incl. nodes copy)
    msg_kernel<<<dim3(NN, 4, B), 256, 0, stream>>>(adjn, nodes, Arow);
    // 9. Bcat = [W_rel (2128x512); W_self (532x512)]
    hipMemcpyAsync(Bcat, W_rel, (size_t)4 * ND * EMB * sizeof(float),
                   hipMemcpyDeviceToDevice, stream);
    hipMemcpyAsync(Bcat + (size_t)4 * ND * EMB, W_self, (size_t)ND * EMB * sizeof(float),
                   hipMemcpyDeviceToDevice, stream);
    // 10. gcn = relu(Arow @ Bcat + b_rgcn)   (M=472, N=512, K=2660)
    gemm_kernel<<<dim3(8, 8), 256, 0, stream>>>(Arow, Bcat, b_rgcn, gcnb, B * NN, EMB,
                                                KCAT, 1);
    // 11. x[b,d,i,k]
    pairwise_kernel<<<dim3(EMB, B), 512, 0, stream>>>(gcnb, ectx, xbuf);
    // 12. conv1: Cin=512, Cout=256, CH=128 -> 4 chunks, grid 4x8x16 = 512 blocks
    conv5g_kernel<<<dim3(4, 8, B * 4), 256, 0, stream>>>(xbuf, conv1_w, part, 512, 256, 128);
    reduce_bias_relu_kernel<<<(B * 256 * 484 + 255) / 256, 256, 0, stream>>>(
        part, conv1_b, y1, 256, 4);
    // 13. conv2: Cin=256, Cout=256, CH=64 -> 4 chunks, grid 4x8x16 = 512 blocks
    conv5g_kernel<<<dim3(4, 8, B * 4), 256, 0, stream>>>(y1, conv2_w, part, 256, 256, 64);
    reduce_bias_relu_kernel<<<(B * 256 * 484 + 255) / 256, 256, 0, stream>>>(
        part, conv2_b, y2, 256, 4);
    // 14. conv3: Cin=256, Cout=512, CH=128 -> 2 chunks, grid 8x8x8 = 512 blocks
    conv5g_kernel<<<dim3(8, 8, B * 2), 256, 0, stream>>>(y2, conv3_w, part, 256, 512, 128);
    // 15. conv3 reduce + transpose fused
    reduce3_transpose_kernel<<<dim3(16, 16, B), 256, 0, stream>>>(part, conv3_b, mflat, 2);
    // 16. feat gather
    feat_kernel<<<dim3(PP, B), 256, 0, stream>>>(gcnb, mflat, hts, feat);
    // 17. ht = tanh(feat @ ht_W + ht_b)   (M=1848, N=1024, K=2048)
    gemm_kernel<<<dim3(16, 29), 256, 0, stream>>>(feat, ht_W, ht_b, htbuf, B * PP, 1024,
                                                  2048, 2);
    // 18. out = ht @ bil_W + bil_b   (M=1848, N=97, K=1024)
    gemm_kernel<<<dim3(2, 29), 256, 0, stream>>>(htbuf, bil_W, bil_b, out, B * PP, 97,
                                                 1024, 0);
}

// Round 6
// 2646.205 us; speedup vs baseline: 1.3999x; 1.1179x over previous
//
#include <hip/hip_runtime.h>
#include <hip/hip_bf16.h>

// ---------------- constants (problem shapes) ----------------
constexpr int B   = 4;
constexpr int C   = 1024;   // seq len
constexpr int HH  = 768;    // hidden
constexpr int NHD = 12;     // attention heads
constexpr int E   = 22;     // entities
constexpr int MM  = 3;      // mentions per entity
constexpr int LL  = 30;     // links
constexpr int NN  = 118;    // graph nodes
constexpr int PP  = 462;    // pairs
constexpr int EMB = 512;
constexpr int IC  = 256;
constexpr int LS  = 16;
constexpr int ND  = 532;    // emb + 20 (node feature dim)
constexpr int KCAT = 4*ND + ND; // 2660 (RGCN concat K)

// ---------------- kernels ----------------

// attention mean over heads, vectorized: (B,h,c,c) -> (B,c,c)
__global__ __launch_bounds__(256) void att_mean4_kernel(const float4* __restrict__ att,
                                                        float4* __restrict__ out) {
    int idx = blockIdx.x * 256 + threadIdx.x;
    int tot = B * C * C / 4;
    if (idx >= tot) return;
    int b = idx / (C * C / 4), rc = idx % (C * C / 4);
    const float4* p = att + (size_t)b * NHD * (C * C / 4) + rc;
    float sx = 0.f, sy = 0.f, sz = 0.f, sw = 0.f;
#pragma unroll
    for (int hh = 0; hh < NHD; hh++) {
        float4 v = p[(size_t)hh * (C * C / 4)];
        sx += v.x; sy += v.y; sz += v.z; sw += v.w;
    }
    const float inv = 1.0f / NHD;
    float4 r; r.x = sx * inv; r.y = sy * inv; r.z = sz * inv; r.w = sw * inv;
    out[idx] = r;
}

// generic fp32 GEMM: C[M,N] = act(A[M,K] @ Bm[K,N] + bias)
// 64x64 tile, BK=16, 256 threads, 4x4 per thread. act: 0 none, 1 relu, 2 tanh
__global__ __launch_bounds__(256) void gemm_kernel(const float* __restrict__ A,
                                                   const float* __restrict__ Bm,
                                                   const float* __restrict__ bias,
                                                   float* __restrict__ Cc,
                                                   int M, int N, int K, int act) {
    __shared__ __align__(16) float As[16][68];
    __shared__ __align__(16) float Bs[16][68];
    int tid = threadIdx.x;
    int tx = tid & 15, ty = tid >> 4;
    int row0 = blockIdx.y * 64, col0 = blockIdx.x * 64;
    float acc[4][4] = {};
    for (int k0 = 0; k0 < K; k0 += 16) {
#pragma unroll
        for (int pass = 0; pass < 4; pass++) {
            int r = pass * 16 + (tid >> 4);
            int gr = row0 + r, gk = k0 + (tid & 15);
            As[tid & 15][r] = (gr < M && gk < K) ? A[(size_t)gr * K + gk] : 0.f;
        }
#pragma unroll
        for (int pass = 0; pass < 4; pass++) {
            int kk = pass * 4 + (tid >> 6);
            int cc = tid & 63;
            int gk = k0 + kk, gc = col0 + cc;
            Bs[kk][cc] = (gk < K && gc < N) ? Bm[(size_t)gk * N + gc] : 0.f;
        }
        __syncthreads();
#pragma unroll
        for (int kk = 0; kk < 16; kk++) {
            float4 av = *(const float4*)&As[kk][ty * 4];
            float4 bv = *(const float4*)&Bs[kk][tx * 4];
            float a[4] = {av.x, av.y, av.z, av.w};
            float bb[4] = {bv.x, bv.y, bv.z, bv.w};
#pragma unroll
            for (int i = 0; i < 4; i++)
#pragma unroll
                for (int j = 0; j < 4; j++) acc[i][j] += a[i] * bb[j];
        }
        __syncthreads();
    }
#pragma unroll
    for (int i = 0; i < 4; i++) {
        int gr = row0 + ty * 4 + i;
        if (gr >= M) continue;
#pragma unroll
        for (int j = 0; j < 4; j++) {
            int gc = col0 + tx * 4 + j;
            if (gc >= N) continue;
            float v = acc[i][j] + (bias ? bias[gc] : 0.f);
            if (act == 1) v = fmaxf(v, 0.f);
            else if (act == 2) v = tanhf(v);
            Cc[(size_t)gr * N + gc] = v;
        }
    }
}

// split-K GEMM: part[z][M][N] = A[M, krange_z] @ Bm[krange_z, N]
__global__ __launch_bounds__(256) void gemm_splitk_kernel(const float* __restrict__ A,
                                                          const float* __restrict__ Bm,
                                                          float* __restrict__ part,
                                                          int M, int N, int K, int kb) {
    __shared__ __align__(16) float As[16][68];
    __shared__ __align__(16) float Bs[16][68];
    int z = blockIdx.z;
    int kbeg = z * kb;
    int kend = (kbeg + kb < K) ? (kbeg + kb) : K;
    int tid = threadIdx.x;
    int tx = tid & 15, ty = tid >> 4;
    int row0 = blockIdx.y * 64, col0 = blockIdx.x * 64;
    float acc[4][4] = {};
    for (int k0 = kbeg; k0 < kend; k0 += 16) {
#pragma unroll
        for (int pass = 0; pass < 4; pass++) {
            int r = pass * 16 + (tid >> 4);
            int gr = row0 + r, gk = k0 + (tid & 15);
            As[tid & 15][r] = (gr < M && gk < kend) ? A[(size_t)gr * K + gk] : 0.f;
        }
#pragma unroll
        for (int pass = 0; pass < 4; pass++) {
            int kk = pass * 4 + (tid >> 6);
            int cc = tid & 63;
            int gk = k0 + kk, gc = col0 + cc;
            Bs[kk][cc] = (gk < kend && gc < N) ? Bm[(size_t)gk * N + gc] : 0.f;
        }
        __syncthreads();
#pragma unroll
        for (int kk = 0; kk < 16; kk++) {
            float4 av = *(const float4*)&As[kk][ty * 4];
            float4 bv = *(const float4*)&Bs[kk][tx * 4];
            float a[4] = {av.x, av.y, av.z, av.w};
            float bb[4] = {bv.x, bv.y, bv.z, bv.w};
#pragma unroll
            for (int i = 0; i < 4; i++)
#pragma unroll
                for (int j = 0; j < 4; j++) acc[i][j] += a[i] * bb[j];
        }
        __syncthreads();
    }
    float* dst = part + (size_t)z * M * N;
#pragma unroll
    for (int i = 0; i < 4; i++) {
        int gr = row0 + ty * 4 + i;
        if (gr >= M) continue;
#pragma unroll
        for (int j = 0; j < 4; j++) {
            int gc = col0 + tx * 4 + j;
            if (gc >= N) continue;
            dst[(size_t)gr * N + gc] = acc[i][j];
        }
    }
}

// out[i] = act(bias[i%N] + sum_s part[s][i])
__global__ __launch_bounds__(256) void reduce_sba_kernel(const float* __restrict__ part,
                                                         const float* __restrict__ bias,
                                                         float* __restrict__ out,
                                                         int MN, int N, int S, int act) {
    int idx = blockIdx.x * 256 + threadIdx.x;
    if (idx >= MN) return;
    float s = bias[idx % N];
    for (int z = 0; z < S; z++) s += part[(size_t)z * MN + idx];
    if (act == 1) s = fmaxf(s, 0.f);
    out[idx] = s;
}

// batched variant (blockIdx.z = batch) for small per-batch GEMMs (e_ctx)
__global__ __launch_bounds__(256) void gemmb_kernel(const float* __restrict__ A0,
                                                    const float* __restrict__ B0,
                                                    float* __restrict__ C0,
                                                    int M, int N, int K,
                                                    long sA, long sB, long sC) {
    const float* A = A0 + (size_t)blockIdx.z * sA;
    const float* Bm = B0 + (size_t)blockIdx.z * sB;
    float* Cc = C0 + (size_t)blockIdx.z * sC;
    __shared__ __align__(16) float As[16][68];
    __shared__ __align__(16) float Bs[16][68];
    int tid = threadIdx.x;
    int tx = tid & 15, ty = tid >> 4;
    int row0 = blockIdx.y * 64, col0 = blockIdx.x * 64;
    float acc[4][4] = {};
    for (int k0 = 0; k0 < K; k0 += 16) {
#pragma unroll
        for (int pass = 0; pass < 4; pass++) {
            int r = pass * 16 + (tid >> 4);
            int gr = row0 + r, gk = k0 + (tid & 15);
            As[tid & 15][r] = (gr < M && gk < K) ? A[(size_t)gr * K + gk] : 0.f;
        }
#pragma unroll
        for (int pass = 0; pass < 4; pass++) {
            int kk = pass * 4 + (tid >> 6);
            int cc = tid & 63;
            int gk = k0 + kk, gc = col0 + cc;
            Bs[kk][cc] = (gk < K && gc < N) ? Bm[(size_t)gk * N + gc] : 0.f;
        }
        __syncthreads();
#pragma unroll
        for (int kk = 0; kk < 16; kk++) {
            float4 av = *(const float4*)&As[kk][ty * 4];
            float4 bv = *(const float4*)&Bs[kk][tx * 4];
            float a[4] = {av.x, av.y, av.z, av.w};
            float bb[4] = {bv.x, bv.y, bv.z, bv.w};
#pragma unroll
            for (int i = 0; i < 4; i++)
#pragma unroll
                for (int j = 0; j < 4; j++) acc[i][j] += a[i] * bb[j];
        }
        __syncthreads();
    }
#pragma unroll
    for (int i = 0; i < 4; i++) {
        int gr = row0 + ty * 4 + i;
        if (gr >= M) continue;
#pragma unroll
        for (int j = 0; j < 4; j++) {
            int gc = col0 + tx * 4 + j;
            if (gc >= N) continue;
            Cc[(size_t)gr * N + gc] = acc[i][j];
        }
    }
}

// fill nodes rows 0..87 (entity logsumexp + mention copies) and type-embed cols for ALL rows
__global__ __launch_bounds__(256) void nodes_fill_kernel(const float* __restrict__ seq,
                                                         const int* __restrict__ mention_idx,
                                                         const int* __restrict__ node_types,
                                                         const float* __restrict__ type_embed,
                                                         float* __restrict__ nodes) {
    int n = blockIdx.x, b = blockIdx.y, t = threadIdx.x;
    float* dst = nodes + ((size_t)b * NN + n) * ND;
    if (n < E) {
        const int* mi = mention_idx + (b * E + n) * MM;
        int i0 = mi[0], i1 = mi[1], i2 = mi[2];
        const float* s0 = seq + ((size_t)b * C + i0) * EMB;
        const float* s1 = seq + ((size_t)b * C + i1) * EMB;
        const float* s2 = seq + ((size_t)b * C + i2) * EMB;
        for (int d = t; d < EMB; d += 256) {
            float v0 = s0[d], v1 = s1[d], v2 = s2[d];
            float mx = fmaxf(v0, fmaxf(v1, v2));
            dst[d] = mx + logf(expf(v0 - mx) + expf(v1 - mx) + expf(v2 - mx));
        }
    } else if (n < E + E * MM) {
        int m = n - E;
        int src = mention_idx[b * E * MM + m];
        const float* sp = seq + ((size_t)b * C + src) * EMB;
        for (int d = t; d < EMB; d += 256) dst[d] = sp[d];
    }
    if (t < 20) {
        int ty_ = node_types[b * NN + n];
        dst[EMB + t] = type_embed[ty_ * 20 + t];
    }
}

// link nodes -> nodes rows 88..117, cols 0..511
__global__ __launch_bounds__(256) void link_nodes_kernel(const float* __restrict__ seq,
                                                         const float* __restrict__ am,
                                                         const int* __restrict__ link_start,
                                                         float* __restrict__ nodes) {
    int l = blockIdx.x, b = blockIdx.y, t = threadIdx.x;
    __shared__ float Ash[LS][LS];
    __shared__ float w[LS];
    int start = link_start[b * LL + l];
    {
        int i = t >> 4, j = t & 15;
        Ash[i][j] = am[((size_t)b * C + start + i) * C + (start + j)];
    }
    __syncthreads();
    if (t < LS) {
        float s = 0.f;
#pragma unroll
        for (int i = 0; i < LS; i++) s += Ash[i][t];
        w[t] = s * (1.0f / LS);
    }
    __syncthreads();
    float* dst = nodes + ((size_t)b * NN + (E + E * MM) + l) * ND;
    for (int d = t; d < EMB; d += 256) {
        float acc = 0.f;
#pragma unroll
        for (int j = 0; j < LS; j++) acc += w[j] * seq[((size_t)b * C + start + j) * EMB + d];
        dst[d] = acc;
    }
}

// ea[b,e,:] = normalize( mean_m att_mean[b, mf[b,e,m], :] )
__global__ __launch_bounds__(256) void ea_kernel(const float* __restrict__ am,
                                                 const int* __restrict__ mention_idx,
                                                 float* __restrict__ ea) {
    int e = blockIdx.x, b = blockIdx.y, t = threadIdx.x;
    const int* mi = mention_idx + (b * E + e) * MM;
    int i0 = mi[0], i1 = mi[1], i2 = mi[2];
    const float* r0 = am + ((size_t)b * C + i0) * C;
    const float* r1 = am + ((size_t)b * C + i1) * C;
    const float* r2 = am + ((size_t)b * C + i2) * C;
    float* dst = ea + ((size_t)b * E + e) * C;
    __shared__ float red[256];
    float psum = 0.f;
    for (int ct = t; ct < C; ct += 256) {
        float v = (r0[ct] + r1[ct] + r2[ct]) * (1.0f / 3.0f);
        dst[ct] = v;
        psum += v;
    }
    red[t] = psum;
    __syncthreads();
    for (int s = 128; s > 0; s >>= 1) {
        if (t < s) red[t] += red[t + s];
        __syncthreads();
    }
    float inv = 1.0f / (red[0] + 1e-5f);
    for (int ct = t; ct < C; ct += 256) dst[ct] *= inv;
}

// adjacency row-normalize
__global__ __launch_bounds__(128) void adjn_kernel(const float* __restrict__ adj,
                                                   float* __restrict__ adjn) {
    int row = blockIdx.x;  // b*4*NN rows
    int t = threadIdx.x;
    const float* src = adj + (size_t)row * NN;
    __shared__ float red[128];
    float s = (t < NN) ? src[t] : 0.f;
    red[t] = s;
    __syncthreads();
    for (int st = 64; st > 0; st >>= 1) {
        if (t < st) red[t] += red[t + st];
        __syncthreads();
    }
    float inv = 1.0f / (red[0] + 1e-5f);
    if (t < NN) adjn[(size_t)row * NN + t] = src[t] * inv;
}

// msg[b,r,i,:] = sum_j adjn[b,r,i,j]*nodes[b,j,:]  -> Arow[b*NN+i][r*ND + d]
__global__ __launch_bounds__(256) void msg_kernel(const float* __restrict__ adjn,
                                                  const float* __restrict__ nodes,
                                                  float* __restrict__ Arow) {
    int i = blockIdx.x, r = blockIdx.y, b = blockIdx.z;
    int t = threadIdx.x;
    __shared__ float a_sh[NN];
    if (t < NN) a_sh[t] = adjn[(((size_t)b * 4 + r) * NN + i) * NN + t];
    __syncthreads();
    float* dst = Arow + ((size_t)b * NN + i) * KCAT;
    const float* nb = nodes + (size_t)b * NN * ND;
    for (int d = t; d < ND; d += 256) {
        float acc = 0.f;
        for (int j = 0; j < NN; j++) acc += a_sh[j] * nb[(size_t)j * ND + d];
        dst[r * ND + d] = acc;
        if (r == 0) dst[4 * ND + d] = nb[(size_t)i * ND + d];
    }
}

// x[b,d,i,k] = ent[i,d]*ent[k,d] + ectx[i,d]*ectx[k,d]
__global__ __launch_bounds__(512) void pairwise_kernel(const float* __restrict__ gcn,
                                                       const float* __restrict__ ectx,
                                                       float* __restrict__ x) {
    int d = blockIdx.x, b = blockIdx.y, t = threadIdx.x;
    __shared__ float ev[E], cv[E];
    if (t < E) ev[t] = gcn[((size_t)b * NN + t) * EMB + d];
    else if (t < 2 * E) cv[t - E] = ectx[((size_t)b * E + (t - E)) * EMB + d];
    __syncthreads();
    if (t < E * E) {
        int i = t / E, k = t % E;
        x[((size_t)b * EMB + d) * (E * E) + t] = ev[i] * ev[k] + cv[i] * cv[k];
    }
}

// implicit-GEMM 5x5 SAME conv, quad-based position tiling.
// block: 32 couts x 128 positions (32 quads of 4 aligned cols), 256 threads.
// each thread: 2 couts x 8 positions (2 quads). Channel group G=4 per barrier pair.
// grid: (Cout/32, 5 quad-tiles, B*nch). Partials to part[z][Cout][484].
__global__ __launch_bounds__(256) void conv5i_kernel(const float* __restrict__ in,
                                                     const float* __restrict__ w,
                                                     float* __restrict__ part,
                                                     int Cin, int Cout, int CH) {
    constexpr int G = 4;
    int nch = Cin / CH;
    int z = blockIdx.z;
    int b = z / nch, ch = z - b * nch;
    int co0 = blockIdx.x * 32;
    int q0 = blockIdx.y * 32;      // first quad index (132 total quads)
    int r0 = q0 / 6;               // first output row of this tile
    int t = threadIdx.x;
    int tx = t & 15, ty = t >> 4;

    __shared__ __align__(16) float As[G * 25 * 34];  // [g][tap][co], stride 34
    __shared__ __align__(16) float Pl[G * 10 * 28];  // [g][in-row][in-col(+2 pad)]

    int qA = q0 + tx, qB = q0 + 16 + tx;
    int rrA = qA / 6 - r0, cA = (qA % 6) * 4;
    int rrB = qB / 6 - r0, cB = (qB % 6) * 4;

    float accA0[4] = {}, accA1[4] = {}, accB0[4] = {}, accB1[4] = {};

    const float* inb = in + ((size_t)b * Cin + ch * CH) * 484;
    const float* wb  = w + ((size_t)co0 * Cin + (size_t)ch * CH) * 25;

    for (int c0 = 0; c0 < CH; c0 += G) {
        __syncthreads();
        // stage G padded input row-bands (10 rows x 28 cols each)
        for (int idx = t; idx < G * 280; idx += 256) {
            int g = idx / 280, rem = idx - g * 280;
            int r = rem / 28, c = rem - r * 28;
            int ih = r0 - 2 + r, iw = c - 2;
            float v = 0.f;
            if (ih >= 0 && ih < 22 && iw >= 0 && iw < 22)
                v = inb[(size_t)(c0 + g) * 484 + ih * 22 + iw];
            Pl[(g * 10 + r) * 28 + c] = v;
        }
        // stage G weight slabs (25 taps x 32 couts each)
        for (int idx = t; idx < G * 800; idx += 256) {
            int g = idx / 800, rem = idx - g * 800;
            int co = rem / 25, tap = rem - co * 25;
            As[(g * 25 + tap) * 34 + co] = wb[(size_t)co * Cin * 25 + (size_t)(c0 + g) * 25 + tap];
        }
        __syncthreads();
#pragma unroll
        for (int g = 0; g < G; g++) {
            const float* plg = &Pl[g * 280];
            const float* asg = &As[g * 850];
#pragma unroll
            for (int dy = 0; dy < 5; dy++) {
                float4 a0 = *(const float4*)&plg[(rrA + dy) * 28 + cA];
                float4 a1 = *(const float4*)&plg[(rrA + dy) * 28 + cA + 4];
                float4 b0 = *(const float4*)&plg[(rrB + dy) * 28 + cB];
                float4 b1 = *(const float4*)&plg[(rrB + dy) * 28 + cB + 4];
                float ivA[8] = {a0.x, a0.y, a0.z, a0.w, a1.x, a1.y, a1.z, a1.w};
                float ivB[8] = {b0.x, b0.y, b0.z, b0.w, b1.x, b1.y, b1.z, b1.w};
#pragma unroll
                for (int dx = 0; dx < 5; dx++) {
                    float2 wv = *(const float2*)&asg[(dy * 5 + dx) * 34 + ty * 2];
#pragma unroll
                    for (int j = 0; j < 4; j++) {
                        accA0[j] += wv.x * ivA[dx + j];
                        accA1[j] += wv.y * ivA[dx + j];
                        accB0[j] += wv.x * ivB[dx + j];
                        accB1[j] += wv.y * ivB[dx + j];
                    }
                }
            }
        }
    }
    float* dst = part + ((size_t)z * Cout + co0 + ty * 2) * 484;
    int rA = r0 + rrA, rB = r0 + rrB;
    if (qA < 132) {
#pragma unroll
        for (int j = 0; j < 4; j++) {
            int col = cA + j;
            if (col < 22) {
                dst[rA * 22 + col] = accA0[j];
                dst[484 + rA * 22 + col] = accA1[j];
            }
        }
    }
    if (qB < 132) {
#pragma unroll
        for (int j = 0; j < 4; j++) {
            int col = cB + j;
            if (col < 22) {
                dst[rB * 22 + col] = accB0[j];
                dst[484 + rB * 22 + col] = accB1[j];
            }
        }
    }
}

// out[b,co,p] = relu(bias[co] + sum_ch part[(b*nch+ch),co,p])
__global__ __launch_bounds__(256) void reduce_bias_relu_kernel(const float* __restrict__ part,
                                                               const float* __restrict__ bias,
                                                               float* __restrict__ out,
                                                               int Cout, int nch) {
    int idx = blockIdx.x * 256 + threadIdx.x;
    int total = B * Cout * 484;
    if (idx >= total) return;
    int b = idx / (Cout * 484);
    int rem = idx % (Cout * 484);
    int co = rem / 484;
    float s = bias[co];
    const float* p = part + ((size_t)b * nch) * Cout * 484 + rem;
    for (int ch = 0; ch < nch; ch++) s += p[(size_t)ch * Cout * 484];
    out[idx] = fmaxf(s, 0.f);
}

// conv3 reduce + bias + relu + transpose to mflat[(b*484+p)*512+co]  (Cout=512)
__global__ __launch_bounds__(256) void reduce3_transpose_kernel(const float* __restrict__ part,
                                                                const float* __restrict__ bias,
                                                                float* __restrict__ mflat,
                                                                int nch) {
    __shared__ float tl[32][33];
    int b = blockIdx.z;
    int co0 = blockIdx.x * 32, pp0 = blockIdx.y * 32;
    int tx = threadIdx.x % 32, tyy = threadIdx.x / 32;
    for (int i = tyy; i < 32; i += 8) {
        int co = co0 + i, p = pp0 + tx;
        float v = 0.f;
        if (p < 484) {
            v = bias[co];
            const float* src = part + (((size_t)b * nch) * 512 + co) * 484 + p;
            for (int ch = 0; ch < nch; ch++) v += src[(size_t)ch * 512 * 484];
            v = fmaxf(v, 0.f);
        }
        tl[i][tx] = v;
    }
    __syncthreads();
    for (int i = tyy; i < 32; i += 8) {
        int p = pp0 + i, co = co0 + tx;
        if (p < 484) mflat[((size_t)b * 484 + p) * 512 + co] = tl[tx][i];
    }
}

// feat[b,p,:] = [hs, ts, mfe, hs*ts]
__global__ __launch_bounds__(256) void feat_kernel(const float* __restrict__ gcn,
                                                   const float* __restrict__ mflat,
                                                   const int* __restrict__ hts,
                                                   float* __restrict__ feat) {
    int p = blockIdx.x, b = blockIdx.y, t = threadIdx.x;
    int hi = hts[((size_t)b * PP + p) * 2];
    int ti = hts[((size_t)b * PP + p) * 2 + 1];
    const float* hsrc = gcn + ((size_t)b * NN + hi) * EMB;
    const float* tsrc = gcn + ((size_t)b * NN + ti) * EMB;
    const float* msrc = mflat + ((size_t)b * 484 + hi * E + ti) * EMB;
    float* dst = feat + ((size_t)b * PP + p) * (4 * EMB);
    for (int d = t; d < EMB; d += 256) {
        float hv = hsrc[d], tv = tsrc[d];
        dst[d] = hv;
        dst[EMB + d] = tv;
        dst[2 * EMB + d] = msrc[d];
        dst[3 * EMB + d] = hv * tv;
    }
}

// ---------------- launcher ----------------
extern "C" void kernel_launch(void* const* d_in, const int* in_sizes, int n_in,
                              void* d_out, int out_size, void* d_ws, size_t ws_size,
                              hipStream_t stream) {
    const float* sequence_output = (const float*)d_in[0];
    const float* attention      = (const float*)d_in[1];
    const float* adjacency      = (const float*)d_in[2];
    const int*   mention_idx    = (const int*)d_in[3];
    const int*   link_start     = (const int*)d_in[4];
    const int*   node_types     = (const int*)d_in[5];
    const int*   hts            = (const int*)d_in[6];
    const float* W_trans        = (const float*)d_in[7];
    const float* b_trans        = (const float*)d_in[8];
    const float* type_embed     = (const float*)d_in[9];
    const float* W_rel          = (const float*)d_in[10];
    const float* W_self         = (const float*)d_in[11];
    const float* b_rgcn         = (const float*)d_in[12];
    const float* conv1_w        = (const float*)d_in[13];
    const float* conv1_b        = (const float*)d_in[14];
    const float* conv2_w        = (const float*)d_in[15];
    const float* conv2_b        = (const float*)d_in[16];
    const float* conv3_w        = (const float*)d_in[17];
    const float* conv3_b        = (const float*)d_in[18];
    const float* ht_W           = (const float*)d_in[19];
    const float* ht_b           = (const float*)d_in[20];
    const float* bil_W          = (const float*)d_in[21];
    const float* bil_b          = (const float*)d_in[22];
    float* out = (float*)d_out;
    float* ws = (float*)d_ws;

    // ---- workspace layout (float offsets), lifetime-aliased ----
    // proven ws >= 42.7MB (round-1 run); this layout tops at 40.0MB.
    // R1 [0, 4,194,304): att_mean (1-5) -> Arow/Bcat/gcnpart (8-10)
    //                    -> xbuf/y1/y2 (11-14) -> feat (16-17)
    float* att_mean = ws;
    float* Arow    = ws;                    // 1,255,520
    float* Bcat    = ws + 1255520;          // 1,361,920 -> ends 2,617,440
    float* gcnpart = ws + 2617440;          //   966,656 -> ends 3,584,096
    float* xbuf    = ws;                    //   991,232
    float* y1      = ws + 991232;           //   495,616
    float* y2      = ws + 1486848;          //   495,616
    float* feat    = ws;                    // 3,784,704
    // R2 [4,194,304, 8,159,232): seqb (2-6) -> conv partials (12-15) -> htbuf (17-18)
    float* seqb  = ws + 4194304;            // 2,097,152
    float* part  = ws + 4194304;            // 3,964,928
    float* htbuf = ws + 4194304;            // 1,892,352
    // R3 [8,159,232, 9,150,464): mflat (15-16)
    float* mflat = ws + 8159232;            //   991,232
    // R4 persistent smalls
    float* nodes = ws + 9150464;            //   251,104
    float* adjn  = ws + 9401568;            //   222,784
    float* ea    = ws + 9624352;            //    90,112
    float* ectx  = ws + 9714464;            //    45,056
    float* gcnb  = ws + 9759520;            //   241,664 -> ends 10,001,184 (40.0MB)

    // 1. att_mean (float4)
    att_mean4_kernel<<<(B * C * C / 4 + 255) / 256, 256, 0, stream>>>(
        (const float4*)attention, (float4*)att_mean);
    // 2. seq = sequence_output @ W_trans + b_trans   (M=4096, N=512, K=768)
    gemm_kernel<<<dim3(EMB / 64, (B * C) / 64), 256, 0, stream>>>(
        sequence_output, W_trans, b_trans, seqb, B * C, EMB, HH, 0);
    // 3. nodes: entity lse + mention rows + type cols
    nodes_fill_kernel<<<dim3(NN, B), 256, 0, stream>>>(seqb, mention_idx, node_types,
                                                       type_embed, nodes);
    // 4. link node rows
    link_nodes_kernel<<<dim3(LL, B), 256, 0, stream>>>(seqb, att_mean, link_start, nodes);
    // 5. ea (normalized entity attention over context)
    ea_kernel<<<dim3(E, B), 256, 0, stream>>>(att_mean, mention_idx, ea);
    // 6. e_ctx = ea @ seq  (batched, M=22, N=512, K=1024)
    gemmb_kernel<<<dim3(EMB / 64, 1, B), 256, 0, stream>>>(
        ea, seqb, ectx, E, EMB, C, (long)E * C, (long)C * EMB, (long)E * EMB);
    // 7. adjacency normalize
    adjn_kernel<<<B * 4 * NN, 128, 0, stream>>>(adjacency, adjn);
    // 8. msg -> Arow (concat layout, incl. nodes copy)
    msg_kernel<<<dim3(NN, 4, B), 256, 0, stream>>>(adjn, nodes, Arow);
    // 9. Bcat = [W_rel (2128x512); W_self (532x512)]
    hipMemcpyAsync(Bcat, W_rel, (size_t)4 * ND * EMB * sizeof(float),
                   hipMemcpyDeviceToDevice, stream);
    hipMemcpyAsync(Bcat + (size_t)4 * ND * EMB, W_self, (size_t)ND * EMB * sizeof(float),
                   hipMemcpyDeviceToDevice, stream);
    // 10. gcn = relu(Arow @ Bcat + b_rgcn)  (M=472, N=512, K=2660) split-K=4
    gemm_splitk_kernel<<<dim3(8, 8, 4), 256, 0, stream>>>(Arow, Bcat, gcnpart,
                                                          B * NN, EMB, KCAT, 672);
    reduce_sba_kernel<<<(B * NN * EMB + 255) / 256, 256, 0, stream>>>(
        gcnpart, b_rgcn, gcnb, B * NN * EMB, EMB, 4, 1);
    // 11. x[b,d,i,k]
    pairwise_kernel<<<dim3(EMB, B), 512, 0, stream>>>(gcnb, ectx, xbuf);
    // 12. conv1: Cin=512, Cout=256, nch=8 (CH=64) -> grid 8x5x32 = 1280 blocks
    conv5i_kernel<<<dim3(8, 5, B * 8), 256, 0, stream>>>(xbuf, conv1_w, part, 512, 256, 64);
    reduce_bias_relu_kernel<<<(B * 256 * 484 + 255) / 256, 256, 0, stream>>>(
        part, conv1_b, y1, 256, 8);
    // 13. conv2: Cin=256, Cout=256, nch=8 (CH=32) -> grid 8x5x32 = 1280 blocks
    conv5i_kernel<<<dim3(8, 5, B * 8), 256, 0, stream>>>(y1, conv2_w, part, 256, 256, 32);
    reduce_bias_relu_kernel<<<(B * 256 * 484 + 255) / 256, 256, 0, stream>>>(
        part, conv2_b, y2, 256, 8);
    // 14. conv3: Cin=256, Cout=512, nch=4 (CH=64) -> grid 16x5x16 = 1280 blocks
    conv5i_kernel<<<dim3(16, 5, B * 4), 256, 0, stream>>>(y2, conv3_w, part, 256, 512, 64);
    // 15. conv3 reduce + transpose fused
    reduce3_transpose_kernel<<<dim3(16, 16, B), 256, 0, stream>>>(part, conv3_b, mflat, 4);
    // 16. feat gather
    feat_kernel<<<dim3(PP, B), 256, 0, stream>>>(gcnb, mflat, hts, feat);
    // 17. ht = tanh(feat @ ht_W + ht_b)   (M=1848, N=1024, K=2048)
    gemm_kernel<<<dim3(16, 29), 256, 0, stream>>>(feat, ht_W, ht_b, htbuf, B * PP, 1024,
                                                  2048, 2);
    // 18. out = ht @ bil_W + bil_b   (M=1848, N=97, K=1024)
    gemm_kernel<<<dim3(2, 29), 256, 0, stream>>>(htbuf, bil_W, bil_b, out, B * PP, 97,
                                                 1024, 0);
}

// Round 8
// 2240.201 us; speedup vs baseline: 1.6536x; 1.1812x over previous
//
#include <hip/hip_runtime.h>
#include <hip/hip_bf16.h>

// ---------------- constants (problem shapes) ----------------
constexpr int B   = 4;
constexpr int C   = 1024;   // seq len
constexpr int HH  = 768;    // hidden
constexpr int NHD = 12;     // attention heads
constexpr int E   = 22;     // entities
constexpr int MM  = 3;      // mentions per entity
constexpr int LL  = 30;     // links
constexpr int NN  = 118;    // graph nodes
constexpr int PP  = 462;    // pairs
constexpr int EMB = 512;
constexpr int IC  = 256;
constexpr int LS  = 16;
constexpr int ND  = 532;    // emb + 20 (node feature dim)
constexpr int KCAT = 4*ND + ND; // 2660 (RGCN concat K)

// ---------------- kernels ----------------

// attention mean over heads, vectorized: (B,h,c,c) -> (B,c,c)
__global__ __launch_bounds__(256) void att_mean4_kernel(const float4* __restrict__ att,
                                                        float4* __restrict__ out) {
    int idx = blockIdx.x * 256 + threadIdx.x;
    int tot = B * C * C / 4;
    if (idx >= tot) return;
    int b = idx / (C * C / 4), rc = idx % (C * C / 4);
    const float4* p = att + (size_t)b * NHD * (C * C / 4) + rc;
    float sx = 0.f, sy = 0.f, sz = 0.f, sw = 0.f;
#pragma unroll
    for (int hh = 0; hh < NHD; hh++) {
        float4 v = p[(size_t)hh * (C * C / 4)];
        sx += v.x; sy += v.y; sz += v.z; sw += v.w;
    }
    const float inv = 1.0f / NHD;
    float4 r; r.x = sx * inv; r.y = sy * inv; r.z = sz * inv; r.w = sw * inv;
    out[idx] = r;
}

// generic fp32 GEMM: C[M,N] = act(A[M,K] @ Bm[K,N] + bias)
// 64x64 tile, BK=16, 256 threads, 4x4 per thread. act: 0 none, 1 relu, 2 tanh
__global__ __launch_bounds__(256) void gemm_kernel(const float* __restrict__ A,
                                                   const float* __restrict__ Bm,
                                                   const float* __restrict__ bias,
                                                   float* __restrict__ Cc,
                                                   int M, int N, int K, int act) {
    __shared__ __align__(16) float As[16][68];
    __shared__ __align__(16) float Bs[16][68];
    int tid = threadIdx.x;
    int tx = tid & 15, ty = tid >> 4;
    int row0 = blockIdx.y * 64, col0 = blockIdx.x * 64;
    float acc[4][4] = {};
    for (int k0 = 0; k0 < K; k0 += 16) {
#pragma unroll
        for (int pass = 0; pass < 4; pass++) {
            int r = pass * 16 + (tid >> 4);
            int gr = row0 + r, gk = k0 + (tid & 15);
            As[tid & 15][r] = (gr < M && gk < K) ? A[(size_t)gr * K + gk] : 0.f;
        }
#pragma unroll
        for (int pass = 0; pass < 4; pass++) {
            int kk = pass * 4 + (tid >> 6);
            int cc = tid & 63;
            int gk = k0 + kk, gc = col0 + cc;
            Bs[kk][cc] = (gk < K && gc < N) ? Bm[(size_t)gk * N + gc] : 0.f;
        }
        __syncthreads();
#pragma unroll
        for (int kk = 0; kk < 16; kk++) {
            float4 av = *(const float4*)&As[kk][ty * 4];
            float4 bv = *(const float4*)&Bs[kk][tx * 4];
            float a[4] = {av.x, av.y, av.z, av.w};
            float bb[4] = {bv.x, bv.y, bv.z, bv.w};
#pragma unroll
            for (int i = 0; i < 4; i++)
#pragma unroll
                for (int j = 0; j < 4; j++) acc[i][j] += a[i] * bb[j];
        }
        __syncthreads();
    }
#pragma unroll
    for (int i = 0; i < 4; i++) {
        int gr = row0 + ty * 4 + i;
        if (gr >= M) continue;
#pragma unroll
        for (int j = 0; j < 4; j++) {
            int gc = col0 + tx * 4 + j;
            if (gc >= N) continue;
            float v = acc[i][j] + (bias ? bias[gc] : 0.f);
            if (act == 1) v = fmaxf(v, 0.f);
            else if (act == 2) v = tanhf(v);
            Cc[(size_t)gr * N + gc] = v;
        }
    }
}

// split-K GEMM: part[z][M][N] = A[M, krange_z] @ Bm[krange_z, N]
__global__ __launch_bounds__(256) void gemm_splitk_kernel(const float* __restrict__ A,
                                                          const float* __restrict__ Bm,
                                                          float* __restrict__ part,
                                                          int M, int N, int K, int kb) {
    __shared__ __align__(16) float As[16][68];
    __shared__ __align__(16) float Bs[16][68];
    int z = blockIdx.z;
    int kbeg = z * kb;
    int kend = (kbeg + kb < K) ? (kbeg + kb) : K;
    int tid = threadIdx.x;
    int tx = tid & 15, ty = tid >> 4;
    int row0 = blockIdx.y * 64, col0 = blockIdx.x * 64;
    float acc[4][4] = {};
    for (int k0 = kbeg; k0 < kend; k0 += 16) {
#pragma unroll
        for (int pass = 0; pass < 4; pass++) {
            int r = pass * 16 + (tid >> 4);
            int gr = row0 + r, gk = k0 + (tid & 15);
            As[tid & 15][r] = (gr < M && gk < kend) ? A[(size_t)gr * K + gk] : 0.f;
        }
#pragma unroll
        for (int pass = 0; pass < 4; pass++) {
            int kk = pass * 4 + (tid >> 6);
            int cc = tid & 63;
            int gk = k0 + kk, gc = col0 + cc;
            Bs[kk][cc] = (gk < kend && gc < N) ? Bm[(size_t)gk * N + gc] : 0.f;
        }
        __syncthreads();
#pragma unroll
        for (int kk = 0; kk < 16; kk++) {
            float4 av = *(const float4*)&As[kk][ty * 4];
            float4 bv = *(const float4*)&Bs[kk][tx * 4];
            float a[4] = {av.x, av.y, av.z, av.w};
            float bb[4] = {bv.x, bv.y, bv.z, bv.w};
#pragma unroll
            for (int i = 0; i < 4; i++)
#pragma unroll
                for (int j = 0; j < 4; j++) acc[i][j] += a[i] * bb[j];
        }
        __syncthreads();
    }
    float* dst = part + (size_t)z * M * N;
#pragma unroll
    for (int i = 0; i < 4; i++) {
        int gr = row0 + ty * 4 + i;
        if (gr >= M) continue;
#pragma unroll
        for (int j = 0; j < 4; j++) {
            int gc = col0 + tx * 4 + j;
            if (gc >= N) continue;
            dst[(size_t)gr * N + gc] = acc[i][j];
        }
    }
}

// out[i] = act(bias[i%N] + sum_s part[s][i])
__global__ __launch_bounds__(256) void reduce_sba_kernel(const float* __restrict__ part,
                                                         const float* __restrict__ bias,
                                                         float* __restrict__ out,
                                                         int MN, int N, int S, int act) {
    int idx = blockIdx.x * 256 + threadIdx.x;
    if (idx >= MN) return;
    float s = bias[idx % N];
    for (int z = 0; z < S; z++) s += part[(size_t)z * MN + idx];
    if (act == 1) s = fmaxf(s, 0.f);
    out[idx] = s;
}

// batched variant (blockIdx.z = batch) for small per-batch GEMMs (e_ctx)
__global__ __launch_bounds__(256) void gemmb_kernel(const float* __restrict__ A0,
                                                    const float* __restrict__ B0,
                                                    float* __restrict__ C0,
                                                    int M, int N, int K,
                                                    long sA, long sB, long sC) {
    const float* A = A0 + (size_t)blockIdx.z * sA;
    const float* Bm = B0 + (size_t)blockIdx.z * sB;
    float* Cc = C0 + (size_t)blockIdx.z * sC;
    __shared__ __align__(16) float As[16][68];
    __shared__ __align__(16) float Bs[16][68];
    int tid = threadIdx.x;
    int tx = tid & 15, ty = tid >> 4;
    int row0 = blockIdx.y * 64, col0 = blockIdx.x * 64;
    float acc[4][4] = {};
    for (int k0 = 0; k0 < K; k0 += 16) {
#pragma unroll
        for (int pass = 0; pass < 4; pass++) {
            int r = pass * 16 + (tid >> 4);
            int gr = row0 + r, gk = k0 + (tid & 15);
            As[tid & 15][r] = (gr < M && gk < K) ? A[(size_t)gr * K + gk] : 0.f;
        }
#pragma unroll
        for (int pass = 0; pass < 4; pass++) {
            int kk = pass * 4 + (tid >> 6);
            int cc = tid & 63;
            int gk = k0 + kk, gc = col0 + cc;
            Bs[kk][cc] = (gk < K && gc < N) ? Bm[(size_t)gk * N + gc] : 0.f;
        }
        __syncthreads();
#pragma unroll
        for (int kk = 0; kk < 16; kk++) {
            float4 av = *(const float4*)&As[kk][ty * 4];
            float4 bv = *(const float4*)&Bs[kk][tx * 4];
            float a[4] = {av.x, av.y, av.z, av.w};
            float bb[4] = {bv.x, bv.y, bv.z, bv.w};
#pragma unroll
            for (int i = 0; i < 4; i++)
#pragma unroll
                for (int j = 0; j < 4; j++) acc[i][j] += a[i] * bb[j];
        }
        __syncthreads();
    }
#pragma unroll
    for (int i = 0; i < 4; i++) {
        int gr = row0 + ty * 4 + i;
        if (gr >= M) continue;
#pragma unroll
        for (int j = 0; j < 4; j++) {
            int gc = col0 + tx * 4 + j;
            if (gc >= N) continue;
            Cc[(size_t)gr * N + gc] = acc[i][j];
        }
    }
}

// fill nodes rows 0..87 (entity logsumexp + mention copies) and type-embed cols for ALL rows
__global__ __launch_bounds__(256) void nodes_fill_kernel(const float* __restrict__ seq,
                                                         const int* __restrict__ mention_idx,
                                                         const int* __restrict__ node_types,
                                                         const float* __restrict__ type_embed,
                                                         float* __restrict__ nodes) {
    int n = blockIdx.x, b = blockIdx.y, t = threadIdx.x;
    float* dst = nodes + ((size_t)b * NN + n) * ND;
    if (n < E) {
        const int* mi = mention_idx + (b * E + n) * MM;
        int i0 = mi[0], i1 = mi[1], i2 = mi[2];
        const float* s0 = seq + ((size_t)b * C + i0) * EMB;
        const float* s1 = seq + ((size_t)b * C + i1) * EMB;
        const float* s2 = seq + ((size_t)b * C + i2) * EMB;
        for (int d = t; d < EMB; d += 256) {
            float v0 = s0[d], v1 = s1[d], v2 = s2[d];
            float mx = fmaxf(v0, fmaxf(v1, v2));
            dst[d] = mx + logf(expf(v0 - mx) + expf(v1 - mx) + expf(v2 - mx));
        }
    } else if (n < E + E * MM) {
        int m = n - E;
        int src = mention_idx[b * E * MM + m];
        const float* sp = seq + ((size_t)b * C + src) * EMB;
        for (int d = t; d < EMB; d += 256) dst[d] = sp[d];
    }
    if (t < 20) {
        int ty_ = node_types[b * NN + n];
        dst[EMB + t] = type_embed[ty_ * 20 + t];
    }
}

// link nodes -> nodes rows 88..117, cols 0..511
__global__ __launch_bounds__(256) void link_nodes_kernel(const float* __restrict__ seq,
                                                         const float* __restrict__ am,
                                                         const int* __restrict__ link_start,
                                                         float* __restrict__ nodes) {
    int l = blockIdx.x, b = blockIdx.y, t = threadIdx.x;
    __shared__ float Ash[LS][LS];
    __shared__ float w[LS];
    int start = link_start[b * LL + l];
    {
        int i = t >> 4, j = t & 15;
        Ash[i][j] = am[((size_t)b * C + start + i) * C + (start + j)];
    }
    __syncthreads();
    if (t < LS) {
        float s = 0.f;
#pragma unroll
        for (int i = 0; i < LS; i++) s += Ash[i][t];
        w[t] = s * (1.0f / LS);
    }
    __syncthreads();
    float* dst = nodes + ((size_t)b * NN + (E + E * MM) + l) * ND;
    for (int d = t; d < EMB; d += 256) {
        float acc = 0.f;
#pragma unroll
        for (int j = 0; j < LS; j++) acc += w[j] * seq[((size_t)b * C + start + j) * EMB + d];
        dst[d] = acc;
    }
}

// ea[b,e,:] = normalize( mean_m att_mean[b, mf[b,e,m], :] )
__global__ __launch_bounds__(256) void ea_kernel(const float* __restrict__ am,
                                                 const int* __restrict__ mention_idx,
                                                 float* __restrict__ ea) {
    int e = blockIdx.x, b = blockIdx.y, t = threadIdx.x;
    const int* mi = mention_idx + (b * E + e) * MM;
    int i0 = mi[0], i1 = mi[1], i2 = mi[2];
    const float* r0 = am + ((size_t)b * C + i0) * C;
    const float* r1 = am + ((size_t)b * C + i1) * C;
    const float* r2 = am + ((size_t)b * C + i2) * C;
    float* dst = ea + ((size_t)b * E + e) * C;
    __shared__ float red[256];
    float psum = 0.f;
    for (int ct = t; ct < C; ct += 256) {
        float v = (r0[ct] + r1[ct] + r2[ct]) * (1.0f / 3.0f);
        dst[ct] = v;
        psum += v;
    }
    red[t] = psum;
    __syncthreads();
    for (int s = 128; s > 0; s >>= 1) {
        if (t < s) red[t] += red[t + s];
        __syncthreads();
    }
    float inv = 1.0f / (red[0] + 1e-5f);
    for (int ct = t; ct < C; ct += 256) dst[ct] *= inv;
}

// adjacency row-normalize
__global__ __launch_bounds__(128) void adjn_kernel(const float* __restrict__ adj,
                                                   float* __restrict__ adjn) {
    int row = blockIdx.x;  // b*4*NN rows
    int t = threadIdx.x;
    const float* src = adj + (size_t)row * NN;
    __shared__ float red[128];
    float s = (t < NN) ? src[t] : 0.f;
    red[t] = s;
    __syncthreads();
    for (int st = 64; st > 0; st >>= 1) {
        if (t < st) red[t] += red[t + st];
        __syncthreads();
    }
    float inv = 1.0f / (red[0] + 1e-5f);
    if (t < NN) adjn[(size_t)row * NN + t] = src[t] * inv;
}

// msg[b,r,i,:] = sum_j adjn[b,r,i,j]*nodes[b,j,:]  -> Arow[b*NN+i][r*ND + d]
__global__ __launch_bounds__(256) void msg_kernel(const float* __restrict__ adjn,
                                                  const float* __restrict__ nodes,
                                                  float* __restrict__ Arow) {
    int i = blockIdx.x, r = blockIdx.y, b = blockIdx.z;
    int t = threadIdx.x;
    __shared__ float a_sh[NN];
    if (t < NN) a_sh[t] = adjn[(((size_t)b * 4 + r) * NN + i) * NN + t];
    __syncthreads();
    float* dst = Arow + ((size_t)b * NN + i) * KCAT;
    const float* nb = nodes + (size_t)b * NN * ND;
    for (int d = t; d < ND; d += 256) {
        float acc = 0.f;
        for (int j = 0; j < NN; j++) acc += a_sh[j] * nb[(size_t)j * ND + d];
        dst[r * ND + d] = acc;
        if (r == 0) dst[4 * ND + d] = nb[(size_t)i * ND + d];
    }
}

// x[b,d,i,k] = ent[i,d]*ent[k,d] + ectx[i,d]*ectx[k,d]
__global__ __launch_bounds__(512) void pairwise_kernel(const float* __restrict__ gcn,
                                                       const float* __restrict__ ectx,
                                                       float* __restrict__ x) {
    int d = blockIdx.x, b = blockIdx.y, t = threadIdx.x;
    __shared__ float ev[E], cv[E];
    if (t < E) ev[t] = gcn[((size_t)b * NN + t) * EMB + d];
    else if (t < 2 * E) cv[t - E] = ectx[((size_t)b * E + (t - E)) * EMB + d];
    __syncthreads();
    if (t < E * E) {
        int i = t / E, k = t % E;
        x[((size_t)b * EMB + d) * (E * E) + t] = ev[i] * ev[k] + cv[i] * cv[k];
    }
}

// implicit-GEMM 5x5 SAME conv, register-heavy tile.
// block: 64 couts x (8 rows x 24 cols = 48 quads), 256 threads.
// thread: 4 couts (ty*4) x 3 quads (tx, tx+16, tx+32) = 48 accs.
// per (g,dy): 6 input b128 + 5 weight b128 feed 240 FMA (21.8 FMA/LDS-instr).
// grid: (Cout/64, 3 row-tiles, B*nch). Partials to part[z][Cout][484], z=b*nch+ch.
__global__ __launch_bounds__(256) void conv5k_kernel(const float* __restrict__ in,
                                                     const float* __restrict__ w,
                                                     float* __restrict__ part,
                                                     int Cin, int Cout, int CH) {
    constexpr int G = 2;
    int nch = Cin / CH;
    int z = blockIdx.z;
    int b = z / nch, ch = z - b * nch;
    int co0 = blockIdx.x * 64;
    int r0 = blockIdx.y * 8;       // output-row tile: 0, 8, 16
    int t = threadIdx.x;
    int tx = t & 15, ty = t >> 4;

    __shared__ __align__(16) float As[G * 25 * 68];  // [g][tap][co], stride 68
    __shared__ __align__(16) float Pl[G * 12 * 28];  // [g][in-row 12][in-col 28]

    int qr[3], qc[3];
#pragma unroll
    for (int s = 0; s < 3; s++) {
        int q = tx + s * 16;            // 0..47 quad index in tile (8 rows x 6 qcols)
        qr[s] = q / 6;                  // 0..7
        qc[s] = (q - qr[s] * 6) * 4;    // 0,4,8,12,16,20
    }

    float acc[3][4][4] = {};  // [quad][co_i][col_j]

    const float* inb = in + ((size_t)b * Cin + ch * CH) * 484;
    const float* wb  = w + ((size_t)co0 * Cin + (size_t)ch * CH) * 25;

    for (int c0 = 0; c0 < CH; c0 += G) {
        __syncthreads();
        // stage G padded input row-bands (12 rows x 28 cols)
        for (int idx = t; idx < G * 336; idx += 256) {
            int g = idx / 336, rem = idx - g * 336;
            int r = rem / 28, c = rem - r * 28;
            int ih = r0 - 2 + r, iw = c - 2;
            float v = 0.f;
            if (ih >= 0 && ih < 22 && iw >= 0 && iw < 22)
                v = inb[(size_t)(c0 + g) * 484 + ih * 22 + iw];
            Pl[(g * 12 + r) * 28 + c] = v;
        }
        // stage G weight slabs (25 taps x 64 couts, stride 68)
        for (int idx = t; idx < G * 1600; idx += 256) {
            int g = idx / 1600, rem = idx - g * 1600;
            int co = rem / 25, tap = rem - co * 25;
            As[(g * 25 + tap) * 68 + co] = wb[(size_t)co * Cin * 25 + (size_t)(c0 + g) * 25 + tap];
        }
        __syncthreads();
#pragma unroll
        for (int g = 0; g < G; g++) {
            const float* plg = &Pl[g * 336];
            const float* asg = &As[g * 1700];
#pragma unroll
            for (int dy = 0; dy < 5; dy++) {
                float iv[3][8];
#pragma unroll
                for (int s = 0; s < 3; s++) {
                    float4 v0 = *(const float4*)&plg[(qr[s] + dy) * 28 + qc[s]];
                    float4 v1 = *(const float4*)&plg[(qr[s] + dy) * 28 + qc[s] + 4];
                    iv[s][0] = v0.x; iv[s][1] = v0.y; iv[s][2] = v0.z; iv[s][3] = v0.w;
                    iv[s][4] = v1.x; iv[s][5] = v1.y; iv[s][6] = v1.z; iv[s][7] = v1.w;
                }
#pragma unroll
                for (int dx = 0; dx < 5; dx++) {
                    float4 wv = *(const float4*)&asg[(dy * 5 + dx) * 68 + ty * 4];
                    float wf[4] = {wv.x, wv.y, wv.z, wv.w};
#pragma unroll
                    for (int s = 0; s < 3; s++)
#pragma unroll
                        for (int i = 0; i < 4; i++)
#pragma unroll
                            for (int j = 0; j < 4; j++)
                                acc[s][i][j] += wf[i] * iv[s][dx + j];
                }
            }
        }
    }
    float* dst0 = part + ((size_t)z * Cout + co0 + ty * 4) * 484;
#pragma unroll
    for (int s = 0; s < 3; s++) {
        int row = r0 + qr[s];
        if (row >= 22) continue;
#pragma unroll
        for (int i = 0; i < 4; i++) {
            float* dr = dst0 + (size_t)i * 484 + row * 22;
#pragma unroll
            for (int j = 0; j < 4; j++) {
                int col = qc[s] + j;
                if (col < 22) dr[col] = acc[s][i][j];
            }
        }
    }
}

// out[b,co,p] = relu(bias[co] + sum_ch part[(b*nch+ch),co,p])
__global__ __launch_bounds__(256) void reduce_bias_relu_kernel(const float* __restrict__ part,
                                                               const float* __restrict__ bias,
                                                               float* __restrict__ out,
                                                               int Cout, int nch) {
    int idx = blockIdx.x * 256 + threadIdx.x;
    int total = B * Cout * 484;
    if (idx >= total) return;
    int b = idx / (Cout * 484);
    int rem = idx % (Cout * 484);
    int co = rem / 484;
    float s = bias[co];
    const float* p = part + ((size_t)b * nch) * Cout * 484 + rem;
    for (int ch = 0; ch < nch; ch++) s += p[(size_t)ch * Cout * 484];
    out[idx] = fmaxf(s, 0.f);
}

// conv3 reduce + bias + relu + transpose to mflat[(b*484+p)*512+co]  (Cout=512)
__global__ __launch_bounds__(256) void reduce3_transpose_kernel(const float* __restrict__ part,
                                                                const float* __restrict__ bias,
                                                                float* __restrict__ mflat,
                                                                int nch) {
    __shared__ float tl[32][33];
    int b = blockIdx.z;
    int co0 = blockIdx.x * 32, pp0 = blockIdx.y * 32;
    int tx = threadIdx.x % 32, tyy = threadIdx.x / 32;
    for (int i = tyy; i < 32; i += 8) {
        int co = co0 + i, p = pp0 + tx;
        float v = 0.f;
        if (p < 484) {
            v = bias[co];
            const float* src = part + (((size_t)b * nch) * 512 + co) * 484 + p;
            for (int ch = 0; ch < nch; ch++) v += src[(size_t)ch * 512 * 484];
            v = fmaxf(v, 0.f);
        }
        tl[i][tx] = v;
    }
    __syncthreads();
    for (int i = tyy; i < 32; i += 8) {
        int p = pp0 + i, co = co0 + tx;
        if (p < 484) mflat[((size_t)b * 484 + p) * 512 + co] = tl[tx][i];
    }
}

// feat[b,p,:] = [hs, ts, mfe, hs*ts]
__global__ __launch_bounds__(256) void feat_kernel(const float* __restrict__ gcn,
                                                   const float* __restrict__ mflat,
                                                   const int* __restrict__ hts,
                                                   float* __restrict__ feat) {
    int p = blockIdx.x, b = blockIdx.y, t = threadIdx.x;
    int hi = hts[((size_t)b * PP + p) * 2];
    int ti = hts[((size_t)b * PP + p) * 2 + 1];
    const float* hsrc = gcn + ((size_t)b * NN + hi) * EMB;
    const float* tsrc = gcn + ((size_t)b * NN + ti) * EMB;
    const float* msrc = mflat + ((size_t)b * 484 + hi * E + ti) * EMB;
    float* dst = feat + ((size_t)b * PP + p) * (4 * EMB);
    for (int d = t; d < EMB; d += 256) {
        float hv = hsrc[d], tv = tsrc[d];
        dst[d] = hv;
        dst[EMB + d] = tv;
        dst[2 * EMB + d] = msrc[d];
        dst[3 * EMB + d] = hv * tv;
    }
}

// ---------------- launcher ----------------
extern "C" void kernel_launch(void* const* d_in, const int* in_sizes, int n_in,
                              void* d_out, int out_size, void* d_ws, size_t ws_size,
                              hipStream_t stream) {
    const float* sequence_output = (const float*)d_in[0];
    const float* attention      = (const float*)d_in[1];
    const float* adjacency      = (const float*)d_in[2];
    const int*   mention_idx    = (const int*)d_in[3];
    const int*   link_start     = (const int*)d_in[4];
    const int*   node_types     = (const int*)d_in[5];
    const int*   hts            = (const int*)d_in[6];
    const float* W_trans        = (const float*)d_in[7];
    const float* b_trans        = (const float*)d_in[8];
    const float* type_embed     = (const float*)d_in[9];
    const float* W_rel          = (const float*)d_in[10];
    const float* W_self         = (const float*)d_in[11];
    const float* b_rgcn         = (const float*)d_in[12];
    const float* conv1_w        = (const float*)d_in[13];
    const float* conv1_b        = (const float*)d_in[14];
    const float* conv2_w        = (const float*)d_in[15];
    const float* conv2_b        = (const float*)d_in[16];
    const float* conv3_w        = (const float*)d_in[17];
    const float* conv3_b        = (const float*)d_in[18];
    const float* ht_W           = (const float*)d_in[19];
    const float* ht_b           = (const float*)d_in[20];
    const float* bil_W          = (const float*)d_in[21];
    const float* bil_b          = (const float*)d_in[22];
    float* out = (float*)d_out;
    float* ws = (float*)d_ws;

    // ---- workspace layout (float offsets), lifetime-aliased; peak 10,672,928 fl
    // (42.69MB) <= proven 10,685,216 fl (round-1 run).
    float* att_mean = ws;                   // [0, 4,194,304)           s1-s5
    float* Arow    = ws;                    // [0, 1,255,520)           s8-s10
    float* Bcat    = ws + 1255520;          // [..., 2,617,440)         s9-s10
    float* gcnpart = ws + 2617440;          // [..., 3,584,096)         s10
    float* xbuf    = ws;                    // [0, 991,232)             s11-s12
    float* y1      = ws + 991232;           // [..., 1,486,848)         s12-s13
    float* y2      = ws + 1486848;          // [..., 1,982,464)         s13-s14
    float* part    = ws + 1982464;          // [..., 9,912,320)         s12-s15 (7.93M fl)
    float* seqb    = ws + 4194304;          // [..., 6,291,456)         s2-s6 (inside part range, dead by s12)
    float* ea      = ws + 6291456;          // [..., 6,381,568)         s5-s6 (inside part range)
    float* mflat   = ws;                    // [0, 991,232)             s15-s16
    float* feat    = ws + 991232;           // [..., 4,775,936)         s16-s17
    float* htbuf   = ws + 4800000;          // [..., 6,692,352)         s17-s18
    float* nodes   = ws + 9912320;          // [..., 10,163,424)        s3-s8
    float* adjn    = ws + 10163424;         // [..., 10,386,208)        s7-s8
    float* ectx    = ws + 10386208;         // [..., 10,431,264)        s6-s11
    float* gcnb    = ws + 10431264;         // [..., 10,672,928)        s10-s16

    // 1. att_mean (float4)
    att_mean4_kernel<<<(B * C * C / 4 + 255) / 256, 256, 0, stream>>>(
        (const float4*)attention, (float4*)att_mean);
    // 2. seq = sequence_output @ W_trans + b_trans   (M=4096, N=512, K=768)
    gemm_kernel<<<dim3(EMB / 64, (B * C) / 64), 256, 0, stream>>>(
        sequence_output, W_trans, b_trans, seqb, B * C, EMB, HH, 0);
    // 3. nodes: entity lse + mention rows + type cols
    nodes_fill_kernel<<<dim3(NN, B), 256, 0, stream>>>(seqb, mention_idx, node_types,
                                                       type_embed, nodes);
    // 4. link node rows
    link_nodes_kernel<<<dim3(LL, B), 256, 0, stream>>>(seqb, att_mean, link_start, nodes);
    // 5. ea (normalized entity attention over context)
    ea_kernel<<<dim3(E, B), 256, 0, stream>>>(att_mean, mention_idx, ea);
    // 6. e_ctx = ea @ seq  (batched, M=22, N=512, K=1024)
    gemmb_kernel<<<dim3(EMB / 64, 1, B), 256, 0, stream>>>(
        ea, seqb, ectx, E, EMB, C, (long)E * C, (long)C * EMB, (long)E * EMB);
    // 7. adjacency normalize
    adjn_kernel<<<B * 4 * NN, 128, 0, stream>>>(adjacency, adjn);
    // 8. msg -> Arow (concat layout, incl. nodes copy)
    msg_kernel<<<dim3(NN, 4, B), 256, 0, stream>>>(adjn, nodes, Arow);
    // 9. Bcat = [W_rel (2128x512); W_self (532x512)]
    hipMemcpyAsync(Bcat, W_rel, (size_t)4 * ND * EMB * sizeof(float),
                   hipMemcpyDeviceToDevice, stream);
    hipMemcpyAsync(Bcat + (size_t)4 * ND * EMB, W_self, (size_t)ND * EMB * sizeof(float),
                   hipMemcpyDeviceToDevice, stream);
    // 10. gcn = relu(Arow @ Bcat + b_rgcn)  (M=472, N=512, K=2660) split-K=4
    gemm_splitk_kernel<<<dim3(8, 8, 4), 256, 0, stream>>>(Arow, Bcat, gcnpart,
                                                          B * NN, EMB, KCAT, 672);
    reduce_sba_kernel<<<(B * NN * EMB + 255) / 256, 256, 0, stream>>>(
        gcnpart, b_rgcn, gcnb, B * NN * EMB, EMB, 4, 1);
    // 11. x[b,d,i,k]
    pairwise_kernel<<<dim3(EMB, B), 512, 0, stream>>>(gcnb, ectx, xbuf);
    // 12. conv1: Cin=512, Cout=256, nch=16 (CH=32) -> grid 4x3x64 = 768 blocks
    conv5k_kernel<<<dim3(4, 3, B * 16), 256, 0, stream>>>(xbuf, conv1_w, part, 512, 256, 32);
    reduce_bias_relu_kernel<<<(B * 256 * 484 + 255) / 256, 256, 0, stream>>>(
        part, conv1_b, y1, 256, 16);
    // 13. conv2: Cin=256, Cout=256, nch=16 (CH=16) -> grid 4x3x64 = 768 blocks
    conv5k_kernel<<<dim3(4, 3, B * 16), 256, 0, stream>>>(y1, conv2_w, part, 256, 256, 16);
    reduce_bias_relu_kernel<<<(B * 256 * 484 + 255) / 256, 256, 0, stream>>>(
        part, conv2_b, y2, 256, 16);
    // 14. conv3: Cin=256, Cout=512, nch=8 (CH=32) -> grid 8x3x32 = 768 blocks
    conv5k_kernel<<<dim3(8, 3, B * 8), 256, 0, stream>>>(y2, conv3_w, part, 256, 512, 32);
    // 15. conv3 reduce + transpose fused
    reduce3_transpose_kernel<<<dim3(16, 16, B), 256, 0, stream>>>(part, conv3_b, mflat, 8);
    // 16. feat gather
    feat_kernel<<<dim3(PP, B), 256, 0, stream>>>(gcnb, mflat, hts, feat);
    // 17. ht = tanh(feat @ ht_W + ht_b)   (M=1848, N=1024, K=2048)
    gemm_kernel<<<dim3(16, 29), 256, 0, stream>>>(feat, ht_W, ht_b, htbuf, B * PP, 1024,
                                                  2048, 2);
    // 18. out = ht @ bil_W + bil_b   (M=1848, N=97, K=1024)
    gemm_kernel<<<dim3(2, 29), 256, 0, stream>>>(htbuf, bil_W, bil_b, out, B * PP, 97,
                                                 1024, 0);
}

// Round 9
// 1890.320 us; speedup vs baseline: 1.9596x; 1.1851x over previous
//
#include <hip/hip_runtime.h>
#include <hip/hip_bf16.h>

// ---------------- constants (problem shapes) ----------------
constexpr int B   = 4;
constexpr int C   = 1024;   // seq len
constexpr int HH  = 768;    // hidden
constexpr int NHD = 12;     // attention heads
constexpr int E   = 22;     // entities
constexpr int MM  = 3;      // mentions per entity
constexpr int LL  = 30;     // links
constexpr int NN  = 118;    // graph nodes
constexpr int PP  = 462;    // pairs
constexpr int EMB = 512;
constexpr int IC  = 256;
constexpr int LS  = 16;
constexpr int ND  = 532;    // emb + 20 (node feature dim)
constexpr int KCAT = 4*ND + ND; // 2660 (RGCN concat K)

typedef __attribute__((ext_vector_type(8))) short bf16x8;
typedef __attribute__((ext_vector_type(4))) float f32x4;

// ---------------- kernels ----------------

// attention mean over heads, vectorized: (B,h,c,c) -> (B,c,c)
__global__ __launch_bounds__(256) void att_mean4_kernel(const float4* __restrict__ att,
                                                        float4* __restrict__ out) {
    int idx = blockIdx.x * 256 + threadIdx.x;
    int tot = B * C * C / 4;
    if (idx >= tot) return;
    int b = idx / (C * C / 4), rc = idx % (C * C / 4);
    const float4* p = att + (size_t)b * NHD * (C * C / 4) + rc;
    float sx = 0.f, sy = 0.f, sz = 0.f, sw = 0.f;
#pragma unroll
    for (int hh = 0; hh < NHD; hh++) {
        float4 v = p[(size_t)hh * (C * C / 4)];
        sx += v.x; sy += v.y; sz += v.z; sw += v.w;
    }
    const float inv = 1.0f / NHD;
    float4 r; r.x = sx * inv; r.y = sy * inv; r.z = sz * inv; r.w = sw * inv;
    out[idx] = r;
}

// generic fp32 GEMM: C[M,N] = act(A[M,K] @ Bm[K,N] + bias)
// 64x64 tile, BK=16, 256 threads, 4x4 per thread. act: 0 none, 1 relu, 2 tanh
__global__ __launch_bounds__(256) void gemm_kernel(const float* __restrict__ A,
                                                   const float* __restrict__ Bm,
                                                   const float* __restrict__ bias,
                                                   float* __restrict__ Cc,
                                                   int M, int N, int K, int act) {
    __shared__ __align__(16) float As[16][68];
    __shared__ __align__(16) float Bs[16][68];
    int tid = threadIdx.x;
    int tx = tid & 15, ty = tid >> 4;
    int row0 = blockIdx.y * 64, col0 = blockIdx.x * 64;
    float acc[4][4] = {};
    for (int k0 = 0; k0 < K; k0 += 16) {
#pragma unroll
        for (int pass = 0; pass < 4; pass++) {
            int r = pass * 16 + (tid >> 4);
            int gr = row0 + r, gk = k0 + (tid & 15);
            As[tid & 15][r] = (gr < M && gk < K) ? A[(size_t)gr * K + gk] : 0.f;
        }
#pragma unroll
        for (int pass = 0; pass < 4; pass++) {
            int kk = pass * 4 + (tid >> 6);
            int cc = tid & 63;
            int gk = k0 + kk, gc = col0 + cc;
            Bs[kk][cc] = (gk < K && gc < N) ? Bm[(size_t)gk * N + gc] : 0.f;
        }
        __syncthreads();
#pragma unroll
        for (int kk = 0; kk < 16; kk++) {
            float4 av = *(const float4*)&As[kk][ty * 4];
            float4 bv = *(const float4*)&Bs[kk][tx * 4];
            float a[4] = {av.x, av.y, av.z, av.w};
            float bb[4] = {bv.x, bv.y, bv.z, bv.w};
#pragma unroll
            for (int i = 0; i < 4; i++)
#pragma unroll
                for (int j = 0; j < 4; j++) acc[i][j] += a[i] * bb[j];
        }
        __syncthreads();
    }
#pragma unroll
    for (int i = 0; i < 4; i++) {
        int gr = row0 + ty * 4 + i;
        if (gr >= M) continue;
#pragma unroll
        for (int j = 0; j < 4; j++) {
            int gc = col0 + tx * 4 + j;
            if (gc >= N) continue;
            float v = acc[i][j] + (bias ? bias[gc] : 0.f);
            if (act == 1) v = fmaxf(v, 0.f);
            else if (act == 2) v = tanhf(v);
            Cc[(size_t)gr * N + gc] = v;
        }
    }
}

// split-K GEMM: part[z][M][N] = A[M, krange_z] @ Bm[krange_z, N]
__global__ __launch_bounds__(256) void gemm_splitk_kernel(const float* __restrict__ A,
                                                          const float* __restrict__ Bm,
                                                          float* __restrict__ part,
                                                          int M, int N, int K, int kb) {
    __shared__ __align__(16) float As[16][68];
    __shared__ __align__(16) float Bs[16][68];
    int z = blockIdx.z;
    int kbeg = z * kb;
    int kend = (kbeg + kb < K) ? (kbeg + kb) : K;
    int tid = threadIdx.x;
    int tx = tid & 15, ty = tid >> 4;
    int row0 = blockIdx.y * 64, col0 = blockIdx.x * 64;
    float acc[4][4] = {};
    for (int k0 = kbeg; k0 < kend; k0 += 16) {
#pragma unroll
        for (int pass = 0; pass < 4; pass++) {
            int r = pass * 16 + (tid >> 4);
            int gr = row0 + r, gk = k0 + (tid & 15);
            As[tid & 15][r] = (gr < M && gk < kend) ? A[(size_t)gr * K + gk] : 0.f;
        }
#pragma unroll
        for (int pass = 0; pass < 4; pass++) {
            int kk = pass * 4 + (tid >> 6);
            int cc = tid & 63;
            int gk = k0 + kk, gc = col0 + cc;
            Bs[kk][cc] = (gk < kend && gc < N) ? Bm[(size_t)gk * N + gc] : 0.f;
        }
        __syncthreads();
#pragma unroll
        for (int kk = 0; kk < 16; kk++) {
            float4 av = *(const float4*)&As[kk][ty * 4];
            float4 bv = *(const float4*)&Bs[kk][tx * 4];
            float a[4] = {av.x, av.y, av.z, av.w};
            float bb[4] = {bv.x, bv.y, bv.z, bv.w};
#pragma unroll
            for (int i = 0; i < 4; i++)
#pragma unroll
                for (int j = 0; j < 4; j++) acc[i][j] += a[i] * bb[j];
        }
        __syncthreads();
    }
    float* dst = part + (size_t)z * M * N;
#pragma unroll
    for (int i = 0; i < 4; i++) {
        int gr = row0 + ty * 4 + i;
        if (gr >= M) continue;
#pragma unroll
        for (int j = 0; j < 4; j++) {
            int gc = col0 + tx * 4 + j;
            if (gc >= N) continue;
            dst[(size_t)gr * N + gc] = acc[i][j];
        }
    }
}

// out[i] = act(bias[i%N] + sum_s part[s][i])
__global__ __launch_bounds__(256) void reduce_sba_kernel(const float* __restrict__ part,
                                                         const float* __restrict__ bias,
                                                         float* __restrict__ out,
                                                         int MN, int N, int S, int act) {
    int idx = blockIdx.x * 256 + threadIdx.x;
    if (idx >= MN) return;
    float s = bias[idx % N];
    for (int z = 0; z < S; z++) s += part[(size_t)z * MN + idx];
    if (act == 1) s = fmaxf(s, 0.f);
    out[idx] = s;
}

// batched variant (blockIdx.z = batch) for small per-batch GEMMs (e_ctx)
__global__ __launch_bounds__(256) void gemmb_kernel(const float* __restrict__ A0,
                                                    const float* __restrict__ B0,
                                                    float* __restrict__ C0,
                                                    int M, int N, int K,
                                                    long sA, long sB, long sC) {
    const float* A = A0 + (size_t)blockIdx.z * sA;
    const float* Bm = B0 + (size_t)blockIdx.z * sB;
    float* Cc = C0 + (size_t)blockIdx.z * sC;
    __shared__ __align__(16) float As[16][68];
    __shared__ __align__(16) float Bs[16][68];
    int tid = threadIdx.x;
    int tx = tid & 15, ty = tid >> 4;
    int row0 = blockIdx.y * 64, col0 = blockIdx.x * 64;
    float acc[4][4] = {};
    for (int k0 = 0; k0 < K; k0 += 16) {
#pragma unroll
        for (int pass = 0; pass < 4; pass++) {
            int r = pass * 16 + (tid >> 4);
            int gr = row0 + r, gk = k0 + (tid & 15);
            As[tid & 15][r] = (gr < M && gk < K) ? A[(size_t)gr * K + gk] : 0.f;
        }
#pragma unroll
        for (int pass = 0; pass < 4; pass++) {
            int kk = pass * 4 + (tid >> 6);
            int cc = tid & 63;
            int gk = k0 + kk, gc = col0 + cc;
            Bs[kk][cc] = (gk < K && gc < N) ? Bm[(size_t)gk * N + gc] : 0.f;
        }
        __syncthreads();
#pragma unroll
        for (int kk = 0; kk < 16; kk++) {
            float4 av = *(const float4*)&As[kk][ty * 4];
            float4 bv = *(const float4*)&Bs[kk][tx * 4];
            float a[4] = {av.x, av.y, av.z, av.w};
            float bb[4] = {bv.x, bv.y, bv.z, bv.w};
#pragma unroll
            for (int i = 0; i < 4; i++)
#pragma unroll
                for (int j = 0; j < 4; j++) acc[i][j] += a[i] * bb[j];
        }
        __syncthreads();
    }
#pragma unroll
    for (int i = 0; i < 4; i++) {
        int gr = row0 + ty * 4 + i;
        if (gr >= M) continue;
#pragma unroll
        for (int j = 0; j < 4; j++) {
            int gc = col0 + tx * 4 + j;
            if (gc >= N) continue;
            Cc[(size_t)gr * N + gc] = acc[i][j];
        }
    }
}

// transpose + fp32->bf16: Wt[n][k] = bf16(W[k][n])
__global__ __launch_bounds__(256) void transpose_bf16_kernel(const float* __restrict__ W,
                                                             __hip_bfloat16* __restrict__ Wt,
                                                             int K, int N) {
    __shared__ float tl[32][33];
    int k0 = blockIdx.x * 32, n0 = blockIdx.y * 32;
    int tx = threadIdx.x & 31, ty = threadIdx.x >> 5;
    for (int i = ty; i < 32; i += 8) {
        int k = k0 + i, n = n0 + tx;
        tl[i][tx] = (k < K && n < N) ? W[(size_t)k * N + n] : 0.f;
    }
    __syncthreads();
    for (int i = ty; i < 32; i += 8) {
        int n = n0 + i, k = k0 + tx;
        if (n < N && k < K) Wt[(size_t)n * K + k] = __float2bfloat16(tl[tx][i]);
    }
}

// bf16 MFMA GEMM: C[M,N] = act(A @ B + bias).
// A: M x K bf16 row-major. Bt: N x K bf16 row-major (B pre-transposed).
// 64x64 tile, 4 waves (wave w -> rows w*16..w*16+16), K-step 32.
// LDS layout [kh 0..3][row 0..63][8 bf16] -> contiguous 16B frags, conflict-free.
// Frag maps (verified on gfx950): A/B: row|col = lane&15, k = (lane>>4)*8+i.
// C/D: col = lane&15, row = (lane>>4)*4 + reg.
__global__ __launch_bounds__(256) void gemm_mfma_kernel(const __hip_bfloat16* __restrict__ A,
                                                        const __hip_bfloat16* __restrict__ Bt,
                                                        const float* __restrict__ bias,
                                                        float* __restrict__ Cc,
                                                        int M, int N, int K, int act) {
    __shared__ __align__(16) short Asub[4 * 64 * 8];
    __shared__ __align__(16) short Bsub[4 * 64 * 8];
    int t = threadIdx.x;
    int row0 = blockIdx.y * 64, col0 = blockIdx.x * 64;
    int w = t >> 6, l = t & 63;
    int r = t >> 2, kh = t & 3;  // staging role: row 0..63, k-half 0..3
    f32x4 acc[4] = {};
    for (int k0 = 0; k0 < K; k0 += 32) {
        __syncthreads();
        {
            int gr = row0 + r;
            uint4 va = make_uint4(0u, 0u, 0u, 0u);
            if (gr < M) va = *(const uint4*)&A[(size_t)gr * K + k0 + kh * 8];
            *(uint4*)&Asub[(kh * 64 + r) * 8] = va;
            uint4 vb = *(const uint4*)&Bt[(size_t)(col0 + r) * K + k0 + kh * 8];
            *(uint4*)&Bsub[(kh * 64 + r) * 8] = vb;
        }
        __syncthreads();
        bf16x8 a = *(const bf16x8*)&Asub[((l >> 4) * 64 + w * 16 + (l & 15)) * 8];
#pragma unroll
        for (int n = 0; n < 4; n++) {
            bf16x8 b = *(const bf16x8*)&Bsub[((l >> 4) * 64 + n * 16 + (l & 15)) * 8];
            acc[n] = __builtin_amdgcn_mfma_f32_16x16x32_bf16(a, b, acc[n], 0, 0, 0);
        }
    }
#pragma unroll
    for (int n = 0; n < 4; n++) {
        int col = col0 + n * 16 + (l & 15);
        if (col >= N) continue;
#pragma unroll
        for (int i = 0; i < 4; i++) {
            int row = row0 + w * 16 + (l >> 4) * 4 + i;
            if (row >= M) continue;
            float v = acc[n][i] + (bias ? bias[col] : 0.f);
            if (act == 1) v = fmaxf(v, 0.f);
            else if (act == 2) v = tanhf(v);
            Cc[(size_t)row * N + col] = v;
        }
    }
}

// fill nodes rows 0..87 (entity logsumexp + mention copies) and type-embed cols for ALL rows
__global__ __launch_bounds__(256) void nodes_fill_kernel(const float* __restrict__ seq,
                                                         const int* __restrict__ mention_idx,
                                                         const int* __restrict__ node_types,
                                                         const float* __restrict__ type_embed,
                                                         float* __restrict__ nodes) {
    int n = blockIdx.x, b = blockIdx.y, t = threadIdx.x;
    float* dst = nodes + ((size_t)b * NN + n) * ND;
    if (n < E) {
        const int* mi = mention_idx + (b * E + n) * MM;
        int i0 = mi[0], i1 = mi[1], i2 = mi[2];
        const float* s0 = seq + ((size_t)b * C + i0) * EMB;
        const float* s1 = seq + ((size_t)b * C + i1) * EMB;
        const float* s2 = seq + ((size_t)b * C + i2) * EMB;
        for (int d = t; d < EMB; d += 256) {
            float v0 = s0[d], v1 = s1[d], v2 = s2[d];
            float mx = fmaxf(v0, fmaxf(v1, v2));
            dst[d] = mx + logf(expf(v0 - mx) + expf(v1 - mx) + expf(v2 - mx));
        }
    } else if (n < E + E * MM) {
        int m = n - E;
        int src = mention_idx[b * E * MM + m];
        const float* sp = seq + ((size_t)b * C + src) * EMB;
        for (int d = t; d < EMB; d += 256) dst[d] = sp[d];
    }
    if (t < 20) {
        int ty_ = node_types[b * NN + n];
        dst[EMB + t] = type_embed[ty_ * 20 + t];
    }
}

// link nodes -> nodes rows 88..117, cols 0..511
__global__ __launch_bounds__(256) void link_nodes_kernel(const float* __restrict__ seq,
                                                         const float* __restrict__ am,
                                                         const int* __restrict__ link_start,
                                                         float* __restrict__ nodes) {
    int l = blockIdx.x, b = blockIdx.y, t = threadIdx.x;
    __shared__ float Ash[LS][LS];
    __shared__ float w[LS];
    int start = link_start[b * LL + l];
    {
        int i = t >> 4, j = t & 15;
        Ash[i][j] = am[((size_t)b * C + start + i) * C + (start + j)];
    }
    __syncthreads();
    if (t < LS) {
        float s = 0.f;
#pragma unroll
        for (int i = 0; i < LS; i++) s += Ash[i][t];
        w[t] = s * (1.0f / LS);
    }
    __syncthreads();
    float* dst = nodes + ((size_t)b * NN + (E + E * MM) + l) * ND;
    for (int d = t; d < EMB; d += 256) {
        float acc = 0.f;
#pragma unroll
        for (int j = 0; j < LS; j++) acc += w[j] * seq[((size_t)b * C + start + j) * EMB + d];
        dst[d] = acc;
    }
}

// ea[b,e,:] = normalize( mean_m att_mean[b, mf[b,e,m], :] )
__global__ __launch_bounds__(256) void ea_kernel(const float* __restrict__ am,
                                                 const int* __restrict__ mention_idx,
                                                 float* __restrict__ ea) {
    int e = blockIdx.x, b = blockIdx.y, t = threadIdx.x;
    const int* mi = mention_idx + (b * E + e) * MM;
    int i0 = mi[0], i1 = mi[1], i2 = mi[2];
    const float* r0 = am + ((size_t)b * C + i0) * C;
    const float* r1 = am + ((size_t)b * C + i1) * C;
    const float* r2 = am + ((size_t)b * C + i2) * C;
    float* dst = ea + ((size_t)b * E + e) * C;
    __shared__ float red[256];
    float psum = 0.f;
    for (int ct = t; ct < C; ct += 256) {
        float v = (r0[ct] + r1[ct] + r2[ct]) * (1.0f / 3.0f);
        dst[ct] = v;
        psum += v;
    }
    red[t] = psum;
    __syncthreads();
    for (int s = 128; s > 0; s >>= 1) {
        if (t < s) red[t] += red[t + s];
        __syncthreads();
    }
    float inv = 1.0f / (red[0] + 1e-5f);
    for (int ct = t; ct < C; ct += 256) dst[ct] *= inv;
}

// adjacency row-normalize
__global__ __launch_bounds__(128) void adjn_kernel(const float* __restrict__ adj,
                                                   float* __restrict__ adjn) {
    int row = blockIdx.x;  // b*4*NN rows
    int t = threadIdx.x;
    const float* src = adj + (size_t)row * NN;
    __shared__ float red[128];
    float s = (t < NN) ? src[t] : 0.f;
    red[t] = s;
    __syncthreads();
    for (int st = 64; st > 0; st >>= 1) {
        if (t < st) red[t] += red[t + st];
        __syncthreads();
    }
    float inv = 1.0f / (red[0] + 1e-5f);
    if (t < NN) adjn[(size_t)row * NN + t] = src[t] * inv;
}

// msg[b,r,i,:] = sum_j adjn[b,r,i,j]*nodes[b,j,:]  -> Arow[b*NN+i][r*ND + d]
__global__ __launch_bounds__(256) void msg_kernel(const float* __restrict__ adjn,
                                                  const float* __restrict__ nodes,
                                                  float* __restrict__ Arow) {
    int i = blockIdx.x, r = blockIdx.y, b = blockIdx.z;
    int t = threadIdx.x;
    __shared__ float a_sh[NN];
    if (t < NN) a_sh[t] = adjn[(((size_t)b * 4 + r) * NN + i) * NN + t];
    __syncthreads();
    float* dst = Arow + ((size_t)b * NN + i) * KCAT;
    const float* nb = nodes + (size_t)b * NN * ND;
    for (int d = t; d < ND; d += 256) {
        float acc = 0.f;
        for (int j = 0; j < NN; j++) acc += a_sh[j] * nb[(size_t)j * ND + d];
        dst[r * ND + d] = acc;
        if (r == 0) dst[4 * ND + d] = nb[(size_t)i * ND + d];
    }
}

// x[b,d,i,k] = ent[i,d]*ent[k,d] + ectx[i,d]*ectx[k,d]
__global__ __launch_bounds__(512) void pairwise_kernel(const float* __restrict__ gcn,
                                                       const float* __restrict__ ectx,
                                                       float* __restrict__ x) {
    int d = blockIdx.x, b = blockIdx.y, t = threadIdx.x;
    __shared__ float ev[E], cv[E];
    if (t < E) ev[t] = gcn[((size_t)b * NN + t) * EMB + d];
    else if (t < 2 * E) cv[t - E] = ectx[((size_t)b * E + (t - E)) * EMB + d];
    __syncthreads();
    if (t < E * E) {
        int i = t / E, k = t % E;
        x[((size_t)b * EMB + d) * (E * E) + t] = ev[i] * ev[k] + cv[i] * cv[k];
    }
}

// implicit-GEMM 5x5 SAME conv, register-heavy tile (see round-6 notes).
__global__ __launch_bounds__(256) void conv5k_kernel(const float* __restrict__ in,
                                                     const float* __restrict__ w,
                                                     float* __restrict__ part,
                                                     int Cin, int Cout, int CH) {
    constexpr int G = 2;
    int nch = Cin / CH;
    int z = blockIdx.z;
    int b = z / nch, ch = z - b * nch;
    int co0 = blockIdx.x * 64;
    int r0 = blockIdx.y * 8;
    int t = threadIdx.x;
    int tx = t & 15, ty = t >> 4;

    __shared__ __align__(16) float As[G * 25 * 68];
    __shared__ __align__(16) float Pl[G * 12 * 28];

    int qr[3], qc[3];
#pragma unroll
    for (int s = 0; s < 3; s++) {
        int q = tx + s * 16;
        qr[s] = q / 6;
        qc[s] = (q - qr[s] * 6) * 4;
    }

    float acc[3][4][4] = {};

    const float* inb = in + ((size_t)b * Cin + ch * CH) * 484;
    const float* wb  = w + ((size_t)co0 * Cin + (size_t)ch * CH) * 25;

    for (int c0 = 0; c0 < CH; c0 += G) {
        __syncthreads();
        for (int idx = t; idx < G * 336; idx += 256) {
            int g = idx / 336, rem = idx - g * 336;
            int r = rem / 28, c = rem - r * 28;
            int ih = r0 - 2 + r, iw = c - 2;
            float v = 0.f;
            if (ih >= 0 && ih < 22 && iw >= 0 && iw < 22)
                v = inb[(size_t)(c0 + g) * 484 + ih * 22 + iw];
            Pl[(g * 12 + r) * 28 + c] = v;
        }
        for (int idx = t; idx < G * 1600; idx += 256) {
            int g = idx / 1600, rem = idx - g * 1600;
            int co = rem / 25, tap = rem - co * 25;
            As[(g * 25 + tap) * 68 + co] = wb[(size_t)co * Cin * 25 + (size_t)(c0 + g) * 25 + tap];
        }
        __syncthreads();
#pragma unroll
        for (int g = 0; g < G; g++) {
            const float* plg = &Pl[g * 336];
            const float* asg = &As[g * 1700];
#pragma unroll
            for (int dy = 0; dy < 5; dy++) {
                float iv[3][8];
#pragma unroll
                for (int s = 0; s < 3; s++) {
                    float4 v0 = *(const float4*)&plg[(qr[s] + dy) * 28 + qc[s]];
                    float4 v1 = *(const float4*)&plg[(qr[s] + dy) * 28 + qc[s] + 4];
                    iv[s][0] = v0.x; iv[s][1] = v0.y; iv[s][2] = v0.z; iv[s][3] = v0.w;
                    iv[s][4] = v1.x; iv[s][5] = v1.y; iv[s][6] = v1.z; iv[s][7] = v1.w;
                }
#pragma unroll
                for (int dx = 0; dx < 5; dx++) {
                    float4 wv = *(const float4*)&asg[(dy * 5 + dx) * 68 + ty * 4];
                    float wf[4] = {wv.x, wv.y, wv.z, wv.w};
#pragma unroll
                    for (int s = 0; s < 3; s++)
#pragma unroll
                        for (int i = 0; i < 4; i++)
#pragma unroll
                            for (int j = 0; j < 4; j++)
                                acc[s][i][j] += wf[i] * iv[s][dx + j];
                }
            }
        }
    }
    float* dst0 = part + ((size_t)z * Cout + co0 + ty * 4) * 484;
#pragma unroll
    for (int s = 0; s < 3; s++) {
        int row = r0 + qr[s];
        if (row >= 22) continue;
#pragma unroll
        for (int i = 0; i < 4; i++) {
            float* dr = dst0 + (size_t)i * 484 + row * 22;
#pragma unroll
            for (int j = 0; j < 4; j++) {
                int col = qc[s] + j;
                if (col < 22) dr[col] = acc[s][i][j];
            }
        }
    }
}

// out[b,co,p] = relu(bias[co] + sum_ch part[(b*nch+ch),co,p])
__global__ __launch_bounds__(256) void reduce_bias_relu_kernel(const float* __restrict__ part,
                                                               const float* __restrict__ bias,
                                                               float* __restrict__ out,
                                                               int Cout, int nch) {
    int idx = blockIdx.x * 256 + threadIdx.x;
    int total = B * Cout * 484;
    if (idx >= total) return;
    int b = idx / (Cout * 484);
    int rem = idx % (Cout * 484);
    int co = rem / 484;
    float s = bias[co];
    const float* p = part + ((size_t)b * nch) * Cout * 484 + rem;
    for (int ch = 0; ch < nch; ch++) s += p[(size_t)ch * Cout * 484];
    out[idx] = fmaxf(s, 0.f);
}

// conv3 reduce + bias + relu + transpose to mflat[(b*484+p)*512+co]  (Cout=512)
__global__ __launch_bounds__(256) void reduce3_transpose_kernel(const float* __restrict__ part,
                                                                const float* __restrict__ bias,
                                                                float* __restrict__ mflat,
                                                                int nch) {
    __shared__ float tl[32][33];
    int b = blockIdx.z;
    int co0 = blockIdx.x * 32, pp0 = blockIdx.y * 32;
    int tx = threadIdx.x % 32, tyy = threadIdx.x / 32;
    for (int i = tyy; i < 32; i += 8) {
        int co = co0 + i, p = pp0 + tx;
        float v = 0.f;
        if (p < 484) {
            v = bias[co];
            const float* src = part + (((size_t)b * nch) * 512 + co) * 484 + p;
            for (int ch = 0; ch < nch; ch++) v += src[(size_t)ch * 512 * 484];
            v = fmaxf(v, 0.f);
        }
        tl[i][tx] = v;
    }
    __syncthreads();
    for (int i = tyy; i < 32; i += 8) {
        int p = pp0 + i, co = co0 + tx;
        if (p < 484) mflat[((size_t)b * 484 + p) * 512 + co] = tl[tx][i];
    }
}

// feat (bf16): feat[b,p,:] = [hs, ts, mfe, hs*ts]
__global__ __launch_bounds__(256) void feat_bf16_kernel(const float* __restrict__ gcn,
                                                        const float* __restrict__ mflat,
                                                        const int* __restrict__ hts,
                                                        __hip_bfloat16* __restrict__ feat) {
    int p = blockIdx.x, b = blockIdx.y, t = threadIdx.x;
    int hi = hts[((size_t)b * PP + p) * 2];
    int ti = hts[((size_t)b * PP + p) * 2 + 1];
    const float* hsrc = gcn + ((size_t)b * NN + hi) * EMB;
    const float* tsrc = gcn + ((size_t)b * NN + ti) * EMB;
    const float* msrc = mflat + ((size_t)b * 484 + hi * E + ti) * EMB;
    __hip_bfloat16* dst = feat + ((size_t)b * PP + p) * (4 * EMB);
    for (int d = t; d < EMB; d += 256) {
        float hv = hsrc[d], tv = tsrc[d];
        dst[d] = __float2bfloat16(hv);
        dst[EMB + d] = __float2bfloat16(tv);
        dst[2 * EMB + d] = __float2bfloat16(msrc[d]);
        dst[3 * EMB + d] = __float2bfloat16(hv * tv);
    }
}

// ---------------- launcher ----------------
extern "C" void kernel_launch(void* const* d_in, const int* in_sizes, int n_in,
                              void* d_out, int out_size, void* d_ws, size_t ws_size,
                              hipStream_t stream) {
    const float* sequence_output = (const float*)d_in[0];
    const float* attention      = (const float*)d_in[1];
    const float* adjacency      = (const float*)d_in[2];
    const int*   mention_idx    = (const int*)d_in[3];
    const int*   link_start     = (const int*)d_in[4];
    const int*   node_types     = (const int*)d_in[5];
    const int*   hts            = (const int*)d_in[6];
    const float* W_trans        = (const float*)d_in[7];
    const float* b_trans        = (const float*)d_in[8];
    const float* type_embed     = (const float*)d_in[9];
    const float* W_rel          = (const float*)d_in[10];
    const float* W_self         = (const float*)d_in[11];
    const float* b_rgcn         = (const float*)d_in[12];
    const float* conv1_w        = (const float*)d_in[13];
    const float* conv1_b        = (const float*)d_in[14];
    const float* conv2_w        = (const float*)d_in[15];
    const float* conv2_b        = (const float*)d_in[16];
    const float* conv3_w        = (const float*)d_in[17];
    const float* conv3_b        = (const float*)d_in[18];
    const float* ht_W           = (const float*)d_in[19];
    const float* ht_b           = (const float*)d_in[20];
    const float* bil_W          = (const float*)d_in[21];
    const float* bil_b          = (const float*)d_in[22];
    float* out = (float*)d_out;
    float* ws = (float*)d_ws;

    // ---- workspace layout (float offsets), lifetime-aliased; peak 10,672,928 fl
    // (42.69MB) <= proven 10,685,216 fl.
    float* att_mean = ws;                   // [0, 4,194,304)           s1-s5
    float* Arow    = ws;                    // [0, 1,255,520)           s8-s10
    float* Bcat    = ws + 1255520;          // [..., 2,617,440)         s9-s10
    float* gcnpart = ws + 2617440;          // [..., 3,584,096)         s10
    float* xbuf    = ws;                    // [0, 991,232)             s11-s12
    float* y1      = ws + 991232;           // [..., 1,486,848)         s12-s13
    float* y2      = ws + 1486848;          // [..., 1,982,464)         s13-s14
    float* part    = ws + 1982464;          // [..., 9,912,320)         s12-s15 (7.93M fl)
    float* seqb    = ws + 4194304;          // [..., 6,291,456)         s2-s6 (dead by s12)
    float* ea      = ws + 6291456;          // [..., 6,381,568)         s5-s6
    float* mflat   = ws;                    // [0, 991,232)             s15-s16
    __hip_bfloat16* featb = (__hip_bfloat16*)(ws + 991232);   // 1,892,352 fl worth -> [991232, 2883584)  s16-s17
    __hip_bfloat16* htWt  = (__hip_bfloat16*)(ws + 2883584);  // 1,048,576 fl -> [2883584, 3932160)       s16-s17
    float* htbuf   = ws + 4800000;          // [..., 6,692,352)         s17-s18
    float* nodes   = ws + 9912320;          // [..., 10,163,424)        s3-s8
    float* adjn    = ws + 10163424;         // [..., 10,386,208)        s7-s8
    float* ectx    = ws + 10386208;         // [..., 10,431,264)        s6-s11
    float* gcnb    = ws + 10431264;         // [..., 10,672,928)        s10-s16

    // 1. att_mean (float4)
    att_mean4_kernel<<<(B * C * C / 4 + 255) / 256, 256, 0, stream>>>(
        (const float4*)attention, (float4*)att_mean);
    // 2. seq = sequence_output @ W_trans + b_trans   (M=4096, N=512, K=768)
    gemm_kernel<<<dim3(EMB / 64, (B * C) / 64), 256, 0, stream>>>(
        sequence_output, W_trans, b_trans, seqb, B * C, EMB, HH, 0);
    // 3. nodes: entity lse + mention rows + type cols
    nodes_fill_kernel<<<dim3(NN, B), 256, 0, stream>>>(seqb, mention_idx, node_types,
                                                       type_embed, nodes);
    // 4. link node rows
    link_nodes_kernel<<<dim3(LL, B), 256, 0, stream>>>(seqb, att_mean, link_start, nodes);
    // 5. ea (normalized entity attention over context)
    ea_kernel<<<dim3(E, B), 256, 0, stream>>>(att_mean, mention_idx, ea);
    // 6. e_ctx = ea @ seq  (batched, M=22, N=512, K=1024)
    gemmb_kernel<<<dim3(EMB / 64, 1, B), 256, 0, stream>>>(
        ea, seqb, ectx, E, EMB, C, (long)E * C, (long)C * EMB, (long)E * EMB);
    // 7. adjacency normalize
    adjn_kernel<<<B * 4 * NN, 128, 0, stream>>>(adjacency, adjn);
    // 8. msg -> Arow (concat layout, incl. nodes copy)
    msg_kernel<<<dim3(NN, 4, B), 256, 0, stream>>>(adjn, nodes, Arow);
    // 9. Bcat = [W_rel (2128x512); W_self (532x512)]
    hipMemcpyAsync(Bcat, W_rel, (size_t)4 * ND * EMB * sizeof(float),
                   hipMemcpyDeviceToDevice, stream);
    hipMemcpyAsync(Bcat + (size_t)4 * ND * EMB, W_self, (size_t)ND * EMB * sizeof(float),
                   hipMemcpyDeviceToDevice, stream);
    // 10. gcn = relu(Arow @ Bcat + b_rgcn)  (M=472, N=512, K=2660) split-K=4
    gemm_splitk_kernel<<<dim3(8, 8, 4), 256, 0, stream>>>(Arow, Bcat, gcnpart,
                                                          B * NN, EMB, KCAT, 672);
    reduce_sba_kernel<<<(B * NN * EMB + 255) / 256, 256, 0, stream>>>(
        gcnpart, b_rgcn, gcnb, B * NN * EMB, EMB, 4, 1);
    // 11. x[b,d,i,k]
    pairwise_kernel<<<dim3(EMB, B), 512, 0, stream>>>(gcnb, ectx, xbuf);
    // 12. conv1: Cin=512, Cout=256, nch=16 (CH=32) -> grid 4x3x64 = 768 blocks
    conv5k_kernel<<<dim3(4, 3, B * 16), 256, 0, stream>>>(xbuf, conv1_w, part, 512, 256, 32);
    reduce_bias_relu_kernel<<<(B * 256 * 484 + 255) / 256, 256, 0, stream>>>(
        part, conv1_b, y1, 256, 16);
    // 13. conv2: Cin=256, Cout=256, nch=16 (CH=16) -> grid 4x3x64 = 768 blocks
    conv5k_kernel<<<dim3(4, 3, B * 16), 256, 0, stream>>>(y1, conv2_w, part, 256, 256, 16);
    reduce_bias_relu_kernel<<<(B * 256 * 484 + 255) / 256, 256, 0, stream>>>(
        part, conv2_b, y2, 256, 16);
    // 14. conv3: Cin=256, Cout=512, nch=8 (CH=32) -> grid 8x3x32 = 768 blocks
    conv5k_kernel<<<dim3(8, 3, B * 8), 256, 0, stream>>>(y2, conv3_w, part, 256, 512, 32);
    // 15. conv3 reduce + transpose fused
    reduce3_transpose_kernel<<<dim3(16, 16, B), 256, 0, stream>>>(part, conv3_b, mflat, 8);
    // 16. feat gather (bf16) + ht_W transpose->bf16
    feat_bf16_kernel<<<dim3(PP, B), 256, 0, stream>>>(gcnb, mflat, hts, featb);
    transpose_bf16_kernel<<<dim3(2048 / 32, 1024 / 32), 256, 0, stream>>>(ht_W, htWt,
                                                                          2048, 1024);
    // 17. ht = tanh(feat @ ht_W + ht_b)  via bf16 MFMA  (M=1848, N=1024, K=2048)
    gemm_mfma_kernel<<<dim3(16, 29), 256, 0, stream>>>(featb, htWt, ht_b, htbuf,
                                                       B * PP, 1024, 2048, 2);
    // 18. out = ht @ bil_W + bil_b   (M=1848, N=97, K=1024)
    gemm_kernel<<<dim3(2, 29), 256, 0, stream>>>(htbuf, bil_W, bil_b, out, B * PP, 97,
                                                 1024, 0);
}